// Round 3
// baseline (868.739 us; speedup 1.0000x reference)
//
#include <hip/hip_runtime.h>
#include <hip/hip_bf16.h>
#include <math.h>

#define B_ 64
#define L_ 1024
#define D_ 256
#define C_ 128
#define LPMAX 1536
#define K1 2304   // 9 taps * 256
#define K2 1152   // 9 taps * 128

typedef __bf16 bf16x8 __attribute__((ext_vector_type(8)));
typedef float f32x4 __attribute__((ext_vector_type(4)));

__device__ __forceinline__ unsigned short f2bf(float f) {
    __hip_bfloat16 h = __float2bfloat16(f);
    return __builtin_bit_cast(unsigned short, h);
}

__device__ __forceinline__ bf16x8 ldg_bf16x8(const unsigned short* p) {
    uint4 u = *reinterpret_cast<const uint4*>(p);
    return __builtin_bit_cast(bf16x8, u);
}

__device__ __forceinline__ bf16x8 zero_bf16x8() {
    uint4 z = {0u, 0u, 0u, 0u};
    return __builtin_bit_cast(bf16x8, z);
}

__device__ __forceinline__ float gelu_exact(float f) {
    return 0.5f * f * (1.0f + erff(f * 0.70710678118654752440f));
}

// async global->LDS, 16B per lane; LDS dest = wave-uniform base + lane*16
__device__ __forceinline__ void gl16(const unsigned short* g, unsigned short* l) {
    __builtin_amdgcn_global_load_lds(
        (const __attribute__((address_space(1))) unsigned int*)g,
        (__attribute__((address_space(3))) unsigned int*)l, 16, 0, 0);
}

// ---- 1. cast x to bf16 + channel-mean series ----
__global__ void prep_kernel(const float* __restrict__ x, unsigned short* __restrict__ xb,
                            float* __restrict__ series) {
    int row = blockIdx.x * 4 + (threadIdx.x >> 6);
    int lane = threadIdx.x & 63;
    size_t base = (size_t)row * D_ + lane * 4;
    float4 v = *reinterpret_cast<const float4*>(x + base);
    ushort4 o;
    o.x = f2bf(v.x); o.y = f2bf(v.y); o.z = f2bf(v.z); o.w = f2bf(v.w);
    *reinterpret_cast<ushort4*>(xb + base) = o;
    float s = v.x + v.y + v.z + v.w;
    #pragma unroll
    for (int d = 32; d; d >>= 1) s += __shfl_xor(s, d);
    if (lane == 0) series[row] = s * (1.0f / D_);
}

// ---- 2. twiddle table (double) ----
__global__ void tw_kernel(double* __restrict__ tw) {
    int j = blockIdx.x * 256 + threadIdx.x;
    if (j < 1024) {
        double a = -2.0 * 3.14159265358979323846 * (double)j / 1024.0;
        tw[2 * j] = cos(a);
        tw[2 * j + 1] = sin(a);
    }
}

// ---- 3. repack weights to bf16 GEMM layout ----
// W1r[c][tap*256+d], W2r[dout][tap*128+c]
__global__ void repack_kernel(const float* __restrict__ W1, const float* __restrict__ W2,
                              unsigned short* __restrict__ W1r, unsigned short* __restrict__ W2r) {
    int i = blockIdx.x * 256 + threadIdx.x;
    if (i < C_ * K1) {
        int c = i / K1, k = i % K1;
        int tap = k >> 8, d = k & 255;
        int dt = tap / 3, dp = tap % 3;
        W1r[i] = f2bf(W1[((c * D_ + d) * 3 + dt) * 3 + dp]);
    } else {
        int i2 = i - C_ * K1;
        if (i2 < D_ * K2) {
            int dout = i2 / K2, k = i2 % K2;
            int tap = k >> 7, cc = k & 127;
            int dt = tap / 3, dp = tap % 3;
            W2r[i2] = f2bf(W2[((dout * C_ + cc) * 3 + dt) * 3 + dp]);
        }
    }
}

// ---- 4. DFT magnitude^2 (double accumulate) ----
__global__ void dft_kernel(const float* __restrict__ series, const double* __restrict__ tw,
                           float* __restrict__ mag2) {
    int bk = blockIdx.x;
    int k = bk % 513, b = bk / 513;
    int lane = threadIdx.x;
    const float* s = series + (size_t)b * L_;
    double re = 0.0, im = 0.0;
    #pragma unroll 4
    for (int i = 0; i < 16; i++) {
        int l = lane + 64 * i;
        int idx = (k * l) & 1023;
        double sv = (double)s[l];
        re += sv * tw[2 * idx];
        im += sv * tw[2 * idx + 1];
    }
    #pragma unroll
    for (int d = 32; d; d >>= 1) { re += __shfl_down(re, d); im += __shfl_down(im, d); }
    if (lane == 0) mag2[bk] = (k == 0) ? 0.0f : (float)(re * re + im * im);
}

// ---- 5. top-3 (tie -> lowest index, matching lax.top_k) ----
__global__ void topk_kernel(const float* __restrict__ mag2, int* __restrict__ periods) {
    int b = threadIdx.x;
    if (b >= B_) return;
    const float* m = mag2 + b * 513;
    int s0 = -1, s1 = -1;
    for (int j = 0; j < 3; j++) {
        float best = -1.0f; int bi = 0;
        for (int k = 0; k < 513; k++) {
            if (k == s0 || k == s1) continue;
            float v = m[k];
            if (v > best) { best = v; bi = k; }
        }
        if (j == 0) s0 = bi; else if (j == 1) s1 = bi;
        periods[b * 3 + j] = bi + 1;
    }
}

// ---- 6. conv1 (256->128) + bias + GELU, output col-major bf16 ----
// 128x128 tile; B-window (144 cols) per (dt,kk) shared across 3 dp taps;
// A (weights) direct-from-L2 register loads; B-only double-buffered LDS.
__global__ __launch_bounds__(256)
void conv1_kernel(const unsigned short* __restrict__ xb,
                  const unsigned short* __restrict__ W1r,
                  const float* __restrict__ b1,
                  const int* __restrict__ periods,
                  unsigned short* __restrict__ out1g) {
    __shared__ __align__(16) unsigned short lB[2][144 * 64];

    const int blk = blockIdx.x;
    // XCD-grouped decode: all 36 blocks of one b land on one XCD slot
    const int b = (blk & 7) * 8 + ((blk >> 3) & 7);
    const int rest = blk >> 6;          // 0..35
    const int j = rest / 12, tile = rest % 12;
    const int p = periods[b * 3 + j];
    if (p <= 1) return;
    const int T = (L_ + p - 1) / p;
    const int Lp = T * p;
    const int col0 = tile * 128;
    if (col0 >= Lp) return;

    const int tid = threadIdx.x;
    const int w = tid >> 6, lane = tid & 63;
    const int wm = w >> 1, wn = w & 1;
    const int l15 = lane & 15, l4 = lane >> 4;
    const int l8 = lane >> 3, l7 = lane & 7;
    const int schunk = (l7 ^ l8) * 8;   // source chunk swizzle (ushort units)

    const unsigned short* xbb = xb + (size_t)b * L_ * D_;

    int cols[4], ppv[4], ttv[4];
    #pragma unroll
    for (int nf = 0; nf < 4; nf++) {
        cols[nf] = col0 + wn * 64 + nf * 16 + l15;
        ppv[nf] = cols[nf] % p;
        ttv[nf] = cols[nf] / p;
    }

    f32x4 acc[4][4];
    #pragma unroll
    for (int i = 0; i < 4; i++)
        #pragma unroll
        for (int nf = 0; nf < 4; nf++)
            acc[i][nf] = f32x4{0.f, 0.f, 0.f, 0.f};

    // stage B window for step s = dt*4 + kk: cols [col0+(dt-1)p-8, +144), d-slice kk*64
    auto stage = [&](int buf, int s) {
        const int dt = s >> 2, kk = s & 3;
        const int cs = col0 + (dt - 1) * p - 8;
        const int kb = kk * 64 + schunk;
        unsigned short* lb = lB[buf];
        #pragma unroll
        for (int q = 0; q < 5; q++) {
            int ciq = 4 * q + w;
            if (ciq < 18) {
                int t = cs + ciq * 8 + l8;
                t = t < 0 ? 0 : (t > L_ - 1 ? L_ - 1 : t);
                gl16(xbb + (size_t)t * D_ + kb, lb + ciq * 512);
            }
        }
    };

    stage(0, 0);
    __syncthreads();

    for (int s = 0; s < 12; s++) {
        const int cur = s & 1;
        if (s + 1 < 12) stage(cur ^ 1, s + 1);
        const int dt = s >> 2, kk = s & 3;
        const unsigned short* lb = lB[cur];

        #pragma unroll
        for (int dp = 0; dp < 3; dp++) {
            const int tap = dt * 3 + dp;
            bool ok[4];
            #pragma unroll
            for (int nf = 0; nf < 4; nf++) {
                int pd = ppv[nf] + dp, td = ttv[nf] + dt;
                int t = cols[nf] + (dt - 1) * p + dp - 1;
                ok[nf] = (pd >= 1) && (pd <= p) && (td >= 1) && (td <= T) &&
                         (cols[nf] < Lp) && (t < L_);
            }
            bf16x8 Af[2][4];
            #pragma unroll
            for (int ks = 0; ks < 2; ks++)
                #pragma unroll
                for (int i = 0; i < 4; i++)
                    Af[ks][i] = ldg_bf16x8(W1r + (size_t)(wm * 64 + i * 16 + l15) * K1 +
                                           tap * 256 + kk * 64 + ks * 32 + l4 * 8);
            #pragma unroll
            for (int ks = 0; ks < 2; ks++) {
                bf16x8 Bf[4];
                #pragma unroll
                for (int nf = 0; nf < 4; nf++) {
                    int rr = wn * 64 + nf * 16 + l15 + dp + 7;
                    Bf[nf] = *reinterpret_cast<const bf16x8*>(
                        lb + rr * 64 + (((ks * 4 + l4) ^ (rr & 7)) * 8));
                    if (!ok[nf]) Bf[nf] = zero_bf16x8();
                }
                #pragma unroll
                for (int i = 0; i < 4; i++)
                    #pragma unroll
                    for (int nf = 0; nf < 4; nf++)
                        acc[i][nf] = __builtin_amdgcn_mfma_f32_16x16x32_bf16(Af[ks][i], Bf[nf], acc[i][nf], 0, 0, 0);
            }
        }
        __syncthreads();
    }

    const size_t ob = (size_t)(b * 3 + j) * LPMAX * C_;
    #pragma unroll
    for (int i = 0; i < 4; i++) {
        const int ch = wm * 64 + i * 16 + l4 * 4;
        const float4 bias = *reinterpret_cast<const float4*>(b1 + ch);
        #pragma unroll
        for (int nf = 0; nf < 4; nf++) {
            const int c = cols[nf];
            if (c < Lp) {
                ushort4 o;
                o.x = f2bf(gelu_exact(acc[i][nf][0] + bias.x));
                o.y = f2bf(gelu_exact(acc[i][nf][1] + bias.y));
                o.z = f2bf(gelu_exact(acc[i][nf][2] + bias.z));
                o.w = f2bf(gelu_exact(acc[i][nf][3] + bias.w));
                *reinterpret_cast<ushort4*>(out1g + ob + (size_t)c * C_ + ch) = o;
            }
        }
    }
}

// ---- 7. conv2 (128->256) summed over 3 periods + residual; writes y to d_out ----
// Same structure: per (j,dt,kk) B-window shared across 3 dp; A from L2.
__global__ __launch_bounds__(256)
void conv2_kernel(const unsigned short* __restrict__ out1g,
                  const unsigned short* __restrict__ W2r,
                  const float* __restrict__ b2,
                  const int* __restrict__ periods,
                  const float* __restrict__ x,
                  float* __restrict__ yout) {
    __shared__ __align__(16) unsigned short lB[2][144 * 64];

    const int blk = blockIdx.x;
    const int b = (blk & 7) * 8 + ((blk >> 3) & 7);
    const int mh = (blk >> 6) & 1;
    const int tile = blk >> 7;          // 0..7

    const int p0 = periods[b * 3 + 0], p1 = periods[b * 3 + 1], p2 = periods[b * 3 + 2];
    const int T0 = (L_ + p0 - 1) / p0, T1 = (L_ + p1 - 1) / p1, T2 = (L_ + p2 - 1) / p2;
    const int nv = (p0 > 1) + (p1 > 1) + (p2 > 1);

    const int tid = threadIdx.x;
    const int w = tid >> 6, lane = tid & 63;
    const int wm = w >> 1, wn = w & 1;
    const int l15 = lane & 15, l4 = lane >> 4;
    const int l8 = lane >> 3, l7 = lane & 7;
    const int schunk = (l7 ^ l8) * 8;
    const int col0 = tile * 128;

    const unsigned short* o1b0 = out1g + (size_t)(b * 3 + 0) * LPMAX * C_;
    const unsigned short* o1b1 = out1g + (size_t)(b * 3 + 1) * LPMAX * C_;
    const unsigned short* o1b2 = out1g + (size_t)(b * 3 + 2) * LPMAX * C_;

    int cols[4];
    int pv0[4], tv0[4], pv1[4], tv1[4], pv2[4], tv2[4];
    #pragma unroll
    for (int nf = 0; nf < 4; nf++) {
        cols[nf] = col0 + wn * 64 + nf * 16 + l15;
        pv0[nf] = cols[nf] % p0; tv0[nf] = cols[nf] / p0;
        pv1[nf] = cols[nf] % p1; tv1[nf] = cols[nf] / p1;
        pv2[nf] = cols[nf] % p2; tv2[nf] = cols[nf] / p2;
    }

    f32x4 acc[4][4];
    #pragma unroll
    for (int i = 0; i < 4; i++)
        #pragma unroll
        for (int nf = 0; nf < 4; nf++)
            acc[i][nf] = f32x4{0.f, 0.f, 0.f, 0.f};

    // step s in [0,18): jn = s/6, dt = (s%6)>>1, kk = s&1
    auto stage = [&](int buf, int s) {
        const int jn = s / 6, r = s - jn * 6;
        const int dt = r >> 1, kk = r & 1;
        const int pj = (jn == 0) ? p0 : ((jn == 1) ? p1 : p2);
        const unsigned short* bb = (jn == 0) ? o1b0 : ((jn == 1) ? o1b1 : o1b2);
        const int cs = col0 + (dt - 1) * pj - 8;
        const int kb = kk * 64 + schunk;
        unsigned short* lb = lB[buf];
        #pragma unroll
        for (int q = 0; q < 5; q++) {
            int ciq = 4 * q + w;
            if (ciq < 18) {
                int t = cs + ciq * 8 + l8;
                t = t < 0 ? 0 : (t > LPMAX - 1 ? LPMAX - 1 : t);
                gl16(bb + (size_t)t * C_ + kb, lb + ciq * 512);
            }
        }
    };

    stage(0, 0);
    __syncthreads();

    for (int s = 0; s < 18; s++) {
        const int cur = s & 1;
        if (s + 1 < 18) stage(cur ^ 1, s + 1);
        const int jn = s / 6, r = s - jn * 6;
        const int dt = r >> 1, kk = r & 1;
        const int pj = (jn == 0) ? p0 : ((jn == 1) ? p1 : p2);
        const int Tj = (jn == 0) ? T0 : ((jn == 1) ? T1 : T2);
        const unsigned short* lb = lB[cur];

        #pragma unroll
        for (int dp = 0; dp < 3; dp++) {
            const int tap = dt * 3 + dp;
            bool ok[4];
            #pragma unroll
            for (int nf = 0; nf < 4; nf++) {
                int pv = (jn == 0) ? pv0[nf] : ((jn == 1) ? pv1[nf] : pv2[nf]);
                int tv = (jn == 0) ? tv0[nf] : ((jn == 1) ? tv1[nf] : tv2[nf]);
                int pd = pv + dp, td = tv + dt;
                ok[nf] = (pj > 1) && (pd >= 1) && (pd <= pj) && (td >= 1) && (td <= Tj);
            }
            bf16x8 Af[2][4];
            #pragma unroll
            for (int ks = 0; ks < 2; ks++)
                #pragma unroll
                for (int i = 0; i < 4; i++)
                    Af[ks][i] = ldg_bf16x8(W2r + (size_t)(mh * 128 + wm * 64 + i * 16 + l15) * K2 +
                                           tap * 128 + kk * 64 + ks * 32 + l4 * 8);
            #pragma unroll
            for (int ks = 0; ks < 2; ks++) {
                bf16x8 Bf[4];
                #pragma unroll
                for (int nf = 0; nf < 4; nf++) {
                    int rr = wn * 64 + nf * 16 + l15 + dp + 7;
                    Bf[nf] = *reinterpret_cast<const bf16x8*>(
                        lb + rr * 64 + (((ks * 4 + l4) ^ (rr & 7)) * 8));
                    if (!ok[nf]) Bf[nf] = zero_bf16x8();
                }
                #pragma unroll
                for (int i = 0; i < 4; i++)
                    #pragma unroll
                    for (int nf = 0; nf < 4; nf++)
                        acc[i][nf] = __builtin_amdgcn_mfma_f32_16x16x32_bf16(Af[ks][i], Bf[nf], acc[i][nf], 0, 0, 0);
            }
        }
        __syncthreads();
    }

    const float inv3 = 1.0f / 3.0f;
    const float fnv = (float)nv;
    #pragma unroll
    for (int i = 0; i < 4; i++) {
        const int dout = mh * 128 + wm * 64 + i * 16 + l4 * 4;
        const float4 bb = *reinterpret_cast<const float4*>(b2 + dout);
        #pragma unroll
        for (int nf = 0; nf < 4; nf++) {
            const size_t xoff = ((size_t)b * L_ + cols[nf]) * D_ + dout;
            const float4 xr = *reinterpret_cast<const float4*>(x + xoff);
            float4 o;
            o.x = xr.x + (acc[i][nf][0] + fnv * bb.x) * inv3;
            o.y = xr.y + (acc[i][nf][1] + fnv * bb.y) * inv3;
            o.z = xr.z + (acc[i][nf][2] + fnv * bb.z) * inv3;
            o.w = xr.w + (acc[i][nf][3] + fnv * bb.w) * inv3;
            *reinterpret_cast<float4*>(yout + xoff) = o;
        }
    }
}

// ---- 8. LayerNorm in-place on d_out ----
__global__ void ln_kernel(float* __restrict__ y, const float* __restrict__ gamma,
                          const float* __restrict__ beta) {
    int row = blockIdx.x * 4 + (threadIdx.x >> 6);
    int lane = threadIdx.x & 63;
    size_t base = (size_t)row * D_ + lane * 4;
    float4 v = *reinterpret_cast<const float4*>(y + base);
    float s = v.x + v.y + v.z + v.w;
    float s2 = v.x * v.x + v.y * v.y + v.z * v.z + v.w * v.w;
    #pragma unroll
    for (int d = 32; d; d >>= 1) { s += __shfl_xor(s, d); s2 += __shfl_xor(s2, d); }
    float mu = s * (1.0f / D_);
    float var = s2 * (1.0f / D_) - mu * mu;
    float inv = 1.0f / sqrtf(var + 1e-5f);
    float4 g = *reinterpret_cast<const float4*>(gamma + lane * 4);
    float4 be = *reinterpret_cast<const float4*>(beta + lane * 4);
    float4 o;
    o.x = (v.x - mu) * inv * g.x + be.x;
    o.y = (v.y - mu) * inv * g.y + be.y;
    o.z = (v.z - mu) * inv * g.z + be.z;
    o.w = (v.w - mu) * inv * g.w + be.w;
    *reinterpret_cast<float4*>(y + base) = o;
}

extern "C" void kernel_launch(void* const* d_in, const int* in_sizes, int n_in,
                              void* d_out, int out_size, void* d_ws, size_t ws_size,
                              hipStream_t stream) {
    const float* x     = (const float*)d_in[0];
    const float* W1    = (const float*)d_in[1];
    const float* b1    = (const float*)d_in[2];
    const float* W2    = (const float*)d_in[3];
    const float* b2    = (const float*)d_in[4];
    const float* gamma = (const float*)d_in[5];
    const float* beta  = (const float*)d_in[6];
    float* out = (float*)d_out;

    char* ws = (char*)d_ws;
    size_t off = 0;
    auto walloc = [&](size_t bytes) -> void* {
        void* pp = ws + off;
        off += (bytes + 255) & ~(size_t)255;
        return pp;
    };
    unsigned short* xb    = (unsigned short*)walloc((size_t)B_ * L_ * D_ * 2);
    unsigned short* out1g = (unsigned short*)walloc((size_t)B_ * 3 * LPMAX * C_ * 2);
    float* series         = (float*)walloc((size_t)B_ * L_ * 4);
    float* mag2           = (float*)walloc((size_t)B_ * 513 * 4);
    int* periods          = (int*)walloc((size_t)B_ * 3 * 4);
    double* tw            = (double*)walloc(1024 * 16);
    unsigned short* W1r   = (unsigned short*)walloc((size_t)C_ * K1 * 2);
    unsigned short* W2r   = (unsigned short*)walloc((size_t)D_ * K2 * 2);

    prep_kernel<<<B_ * L_ / 4, 256, 0, stream>>>(x, xb, series);
    tw_kernel<<<4, 256, 0, stream>>>(tw);
    repack_kernel<<<(C_ * K1 + D_ * K2 + 255) / 256, 256, 0, stream>>>(W1, W2, W1r, W2r);
    dft_kernel<<<B_ * 513, 64, 0, stream>>>(series, tw, mag2);
    topk_kernel<<<1, 64, 0, stream>>>(mag2, periods);
    conv1_kernel<<<B_ * 3 * 12, 256, 0, stream>>>(xb, W1r, b1, periods, out1g);
    conv2_kernel<<<B_ * 16, 256, 0, stream>>>(out1g, W2r, b2, periods, x, out);
    ln_kernel<<<B_ * L_ / 4, 256, 0, stream>>>(out, gamma, beta);
}

// Round 4
// 649.733 us; speedup vs baseline: 1.3371x; 1.3371x over previous
//
#include <hip/hip_runtime.h>
#include <hip/hip_bf16.h>
#include <math.h>

#define B_ 64
#define L_ 1024
#define D_ 256
#define C_ 128
#define LPMAX 1536
#define K1 2304   // 9 taps * 256
#define K2 1152   // 9 taps * 128

typedef __bf16 bf16x8 __attribute__((ext_vector_type(8)));
typedef float f32x4 __attribute__((ext_vector_type(4)));

__device__ __forceinline__ unsigned short f2bf(float f) {
    __hip_bfloat16 h = __float2bfloat16(f);
    return __builtin_bit_cast(unsigned short, h);
}

__device__ __forceinline__ float gelu_exact(float f) {
    return 0.5f * f * (1.0f + erff(f * 0.70710678118654752440f));
}

// async global->LDS: lds dest is wave-uniform base; HW adds lane*16
__device__ __forceinline__ void gl16(const unsigned short* g, unsigned short* l) {
    __builtin_amdgcn_global_load_lds(
        (const __attribute__((address_space(1))) unsigned int*)g,
        (__attribute__((address_space(3))) unsigned int*)l, 16, 0, 0);
}

// ---- 1. cast x to bf16 + channel-mean series ----
__global__ void prep_kernel(const float* __restrict__ x, unsigned short* __restrict__ xb,
                            float* __restrict__ series) {
    int row = blockIdx.x * 4 + (threadIdx.x >> 6);
    int lane = threadIdx.x & 63;
    size_t base = (size_t)row * D_ + lane * 4;
    float4 v = *reinterpret_cast<const float4*>(x + base);
    ushort4 o;
    o.x = f2bf(v.x); o.y = f2bf(v.y); o.z = f2bf(v.z); o.w = f2bf(v.w);
    *reinterpret_cast<ushort4*>(xb + base) = o;
    float s = v.x + v.y + v.z + v.w;
    #pragma unroll
    for (int d = 32; d; d >>= 1) s += __shfl_xor(s, d);
    if (lane == 0) series[row] = s * (1.0f / D_);
}

// ---- 2. twiddle table (double) ----
__global__ void tw_kernel(double* __restrict__ tw) {
    int j = blockIdx.x * 256 + threadIdx.x;
    if (j < 1024) {
        double a = -2.0 * 3.14159265358979323846 * (double)j / 1024.0;
        tw[2 * j] = cos(a);
        tw[2 * j + 1] = sin(a);
    }
}

// ---- 3. repack weights to bf16 GEMM layout ----
__global__ void repack_kernel(const float* __restrict__ W1, const float* __restrict__ W2,
                              unsigned short* __restrict__ W1r, unsigned short* __restrict__ W2r) {
    int i = blockIdx.x * 256 + threadIdx.x;
    if (i < C_ * K1) {
        int c = i / K1, k = i % K1;
        int tap = k >> 8, d = k & 255;
        int dt = tap / 3, dp = tap % 3;
        W1r[i] = f2bf(W1[((c * D_ + d) * 3 + dt) * 3 + dp]);
    } else {
        int i2 = i - C_ * K1;
        if (i2 < D_ * K2) {
            int dout = i2 / K2, k = i2 % K2;
            int tap = k >> 7, cc = k & 127;
            int dt = tap / 3, dp = tap % 3;
            W2r[i2] = f2bf(W2[((dout * C_ + cc) * 3 + dt) * 3 + dp]);
        }
    }
}

// ---- 4. DFT magnitude^2 (double accumulate) ----
__global__ void dft_kernel(const float* __restrict__ series, const double* __restrict__ tw,
                           float* __restrict__ mag2) {
    int bk = blockIdx.x;
    int k = bk % 513, b = bk / 513;
    int lane = threadIdx.x;
    const float* s = series + (size_t)b * L_;
    double re = 0.0, im = 0.0;
    #pragma unroll 4
    for (int i = 0; i < 16; i++) {
        int l = lane + 64 * i;
        int idx = (k * l) & 1023;
        double sv = (double)s[l];
        re += sv * tw[2 * idx];
        im += sv * tw[2 * idx + 1];
    }
    #pragma unroll
    for (int d = 32; d; d >>= 1) { re += __shfl_down(re, d); im += __shfl_down(im, d); }
    if (lane == 0) mag2[bk] = (k == 0) ? 0.0f : (float)(re * re + im * im);
}

// ---- 5. top-3, wave-parallel argmax (tie -> lowest index) ----
__global__ void topk_kernel(const float* __restrict__ mag2, int* __restrict__ periods) {
    int b = blockIdx.x;
    int lane = threadIdx.x;
    const float* m = mag2 + b * 513;
    float v[9]; int kid[9];
    #pragma unroll
    for (int r = 0; r < 9; r++) {
        int k = r * 64 + lane;
        kid[r] = k;
        v[r] = (k < 513) ? m[k] : -1.0f;
    }
    int s0 = -1, s1 = -1;
    for (int j = 0; j < 3; j++) {
        float best = -1.0f; int bi = 0x7fffffff;
        #pragma unroll
        for (int r = 0; r < 9; r++) {
            bool skip = (kid[r] == s0) || (kid[r] == s1) || (kid[r] >= 513);
            if (!skip && (v[r] > best || (v[r] == best && kid[r] < bi))) { best = v[r]; bi = kid[r]; }
        }
        #pragma unroll
        for (int d = 32; d; d >>= 1) {
            float ov = __shfl_xor(best, d);
            int oi = __shfl_xor(bi, d);
            if (ov > best || (ov == best && oi < bi)) { best = ov; bi = oi; }
        }
        if (lane == 0) periods[b * 3 + j] = bi + 1;
        if (j == 0) s0 = bi; else if (j == 1) s1 = bi;
    }
}

// ---- 6. conv1 (256->128) + bias + GELU, output col-major bf16 ----
// 128x128 tile, BK=32, plane-major LDS, mask-free inner loop (zeropad redirect)
__global__ __launch_bounds__(256, 4)
void conv1_kernel(const unsigned short* __restrict__ xb,
                  const unsigned short* __restrict__ W1r,
                  const float* __restrict__ b1,
                  const int* __restrict__ periods,
                  unsigned short* __restrict__ out1g,
                  const unsigned short* __restrict__ zeropad) {
    __shared__ __align__(16) unsigned short lA[2][4096];
    __shared__ __align__(16) unsigned short lB[2][4096];

    const int blk = blockIdx.x;
    const int tile = blk % 12;
    const int bj = blk / 12;
    const int j = bj % 3, b = bj / 3;
    const int p = periods[b * 3 + j];
    if (p <= 1) return;
    const int T = (L_ + p - 1) / p;
    const int Lp = T * p;
    const int col0 = tile * 128;
    if (col0 >= Lp) return;

    const int tid = threadIdx.x;
    const int w = tid >> 6, lane = tid & 63;
    const int wm = w >> 1, wn = w & 1;
    const int l15 = lane & 15, l4 = lane >> 4;

    const unsigned short* xbb = xb + (size_t)b * L_ * D_;

    int cq0 = col0 + lane, cq1 = col0 + 64 + lane;
    int pp0 = cq0 % p, tt0 = cq0 / p;
    int pp1 = cq1 % p, tt1 = cq1 / p;

    int aoff[4], boff[4];
    #pragma unroll
    for (int i = 0; i < 4; i++) aoff[i] = l4 * 1024 + (wm * 64 + i * 16 + l15) * 8;
    #pragma unroll
    for (int nf = 0; nf < 4; nf++) boff[nf] = l4 * 1024 + (wn * 64 + nf * 16 + l15) * 8;

    f32x4 acc[4][4];
    #pragma unroll
    for (int i = 0; i < 4; i++)
        #pragma unroll
        for (int nf = 0; nf < 4; nf++)
            acc[i][nf] = f32x4{0.f, 0.f, 0.f, 0.f};

    const unsigned short* srcB0 = zeropad;
    const unsigned short* srcB1 = zeropad;
    int koffA = 0;

    auto settap = [&](int tap) {
        const int dt = tap / 3, dp = tap - 3 * dt;
        const int off = (dt - 1) * p + dp - 1;
        koffA = tap * 256;
        bool ok0 = (pp0 + dp >= 1) && (pp0 + dp <= p) && (tt0 + dt >= 1) && (tt0 + dt <= T) &&
                   (cq0 < Lp) && (cq0 + off < L_);
        bool ok1 = (pp1 + dp >= 1) && (pp1 + dp <= p) && (tt1 + dt >= 1) && (tt1 + dt <= T) &&
                   (cq1 < Lp) && (cq1 + off < L_);
        srcB0 = ok0 ? (xbb + (size_t)(cq0 + off) * D_) : zeropad;
        srcB1 = ok1 ? (xbb + (size_t)(cq1 + off) * D_) : zeropad;
    };

    auto stage = [&](int buf, int kk) {
        unsigned short* la = lA[buf];
        unsigned short* lb = lB[buf];
        const int kb = kk * 32 + w * 8;
        gl16(W1r + (size_t)lane * K1 + koffA + kb, la + w * 1024);
        gl16(W1r + (size_t)(64 + lane) * K1 + koffA + kb, la + w * 1024 + 512);
        gl16(srcB0 + kb, lb + w * 1024);
        gl16(srcB1 + kb, lb + w * 1024 + 512);
    };

    settap(0);
    stage(0, 0);
    __syncthreads();

    int tap = 0;
    for (int s = 0; s < 72; s++) {
        const int cur = s & 1;
        const int sn = s + 1;
        if (sn < 72) {
            if ((sn & 7) == 0) settap(++tap);
            stage(cur ^ 1, sn & 7);
        }
        const unsigned short* la = lA[cur];
        const unsigned short* lb = lB[cur];
        bf16x8 Af[4], Bf[4];
        #pragma unroll
        for (int i = 0; i < 4; i++) Af[i] = *reinterpret_cast<const bf16x8*>(la + aoff[i]);
        #pragma unroll
        for (int nf = 0; nf < 4; nf++) Bf[nf] = *reinterpret_cast<const bf16x8*>(lb + boff[nf]);
        #pragma unroll
        for (int i = 0; i < 4; i++)
            #pragma unroll
            for (int nf = 0; nf < 4; nf++)
                acc[i][nf] = __builtin_amdgcn_mfma_f32_16x16x32_bf16(Af[i], Bf[nf], acc[i][nf], 0, 0, 0);
        __syncthreads();
    }

    const size_t ob = (size_t)(b * 3 + j) * LPMAX * C_;
    #pragma unroll
    for (int i = 0; i < 4; i++) {
        const int ch = wm * 64 + i * 16 + l4 * 4;
        const float4 bias = *reinterpret_cast<const float4*>(b1 + ch);
        #pragma unroll
        for (int nf = 0; nf < 4; nf++) {
            const int c = col0 + wn * 64 + nf * 16 + l15;
            if (c < Lp) {
                ushort4 o;
                o.x = f2bf(gelu_exact(acc[i][nf][0] + bias.x));
                o.y = f2bf(gelu_exact(acc[i][nf][1] + bias.y));
                o.z = f2bf(gelu_exact(acc[i][nf][2] + bias.z));
                o.w = f2bf(gelu_exact(acc[i][nf][3] + bias.w));
                *reinterpret_cast<ushort4*>(out1g + ob + (size_t)c * C_ + ch) = o;
            }
        }
    }
}

// ---- 7. conv2 (128->256) summed over 3 periods + residual; writes y to d_out ----
__global__ __launch_bounds__(256, 4)
void conv2_kernel(const unsigned short* __restrict__ out1g,
                  const unsigned short* __restrict__ W2r,
                  const float* __restrict__ b2,
                  const int* __restrict__ periods,
                  const float* __restrict__ x,
                  float* __restrict__ yout,
                  const unsigned short* __restrict__ zeropad) {
    __shared__ __align__(16) unsigned short lA[2][4096];
    __shared__ __align__(16) unsigned short lB[2][4096];

    const int blk = blockIdx.x;
    const int mh = blk & 1;
    const int tile = (blk >> 1) & 7;
    const int b = blk >> 4;
    const int col0 = tile * 128;

    const int tid = threadIdx.x;
    const int w = tid >> 6, lane = tid & 63;
    const int wm = w >> 1, wn = w & 1;
    const int l15 = lane & 15, l4 = lane >> 4;

    int cq0 = col0 + lane, cq1 = col0 + 64 + lane;

    int aoff[4], boff[4];
    #pragma unroll
    for (int i = 0; i < 4; i++) aoff[i] = l4 * 1024 + (wm * 64 + i * 16 + l15) * 8;
    #pragma unroll
    for (int nf = 0; nf < 4; nf++) boff[nf] = l4 * 1024 + (wn * 64 + nf * 16 + l15) * 8;

    f32x4 acc[4][4];
    #pragma unroll
    for (int i = 0; i < 4; i++)
        #pragma unroll
        for (int nf = 0; nf < 4; nf++)
            acc[i][nf] = f32x4{0.f, 0.f, 0.f, 0.f};

    int jn = 0, tap9 = 0;
    int pj = periods[b * 3];
    int Tj = (L_ + pj - 1) / pj;
    const unsigned short* bbj = out1g + (size_t)(b * 3) * LPMAX * C_;
    int pp0 = cq0 % pj, tt0 = cq0 / pj;
    int pp1 = cq1 % pj, tt1 = cq1 / pj;
    int nv = 0;
    #pragma unroll
    for (int jj = 0; jj < 3; jj++) nv += (periods[b * 3 + jj] > 1) ? 1 : 0;

    const unsigned short* srcB0 = zeropad;
    const unsigned short* srcB1 = zeropad;
    int koffA = 0;

    auto settap = [&](int tap) {
        const int dt = tap / 3, dp = tap - 3 * dt;
        const int off = (dt - 1) * pj + dp - 1;
        koffA = tap * 128;
        bool okj = pj > 1;
        bool ok0 = okj && (pp0 + dp >= 1) && (pp0 + dp <= pj) && (tt0 + dt >= 1) && (tt0 + dt <= Tj);
        bool ok1 = okj && (pp1 + dp >= 1) && (pp1 + dp <= pj) && (tt1 + dt >= 1) && (tt1 + dt <= Tj);
        srcB0 = ok0 ? (bbj + (size_t)(cq0 + off) * C_) : zeropad;
        srcB1 = ok1 ? (bbj + (size_t)(cq1 + off) * C_) : zeropad;
    };

    auto stage = [&](int buf, int kk) {
        unsigned short* la = lA[buf];
        unsigned short* lb = lB[buf];
        const int kb = kk * 32 + w * 8;
        gl16(W2r + (size_t)(mh * 128 + lane) * K2 + koffA + kb, la + w * 1024);
        gl16(W2r + (size_t)(mh * 128 + 64 + lane) * K2 + koffA + kb, la + w * 1024 + 512);
        gl16(srcB0 + kb, lb + w * 1024);
        gl16(srcB1 + kb, lb + w * 1024 + 512);
    };

    settap(0);
    stage(0, 0);
    __syncthreads();

    for (int s = 0; s < 108; s++) {
        const int cur = s & 1;
        const int sn = s + 1;
        if (sn < 108) {
            if ((sn & 3) == 0) {
                if (++tap9 == 9) {
                    tap9 = 0;
                    jn++;
                    pj = periods[b * 3 + jn];
                    Tj = (L_ + pj - 1) / pj;
                    bbj = out1g + (size_t)(b * 3 + jn) * LPMAX * C_;
                    pp0 = cq0 % pj; tt0 = cq0 / pj;
                    pp1 = cq1 % pj; tt1 = cq1 / pj;
                }
                settap(tap9);
            }
            stage(cur ^ 1, sn & 3);
        }
        const unsigned short* la = lA[cur];
        const unsigned short* lb = lB[cur];
        bf16x8 Af[4], Bf[4];
        #pragma unroll
        for (int i = 0; i < 4; i++) Af[i] = *reinterpret_cast<const bf16x8*>(la + aoff[i]);
        #pragma unroll
        for (int nf = 0; nf < 4; nf++) Bf[nf] = *reinterpret_cast<const bf16x8*>(lb + boff[nf]);
        #pragma unroll
        for (int i = 0; i < 4; i++)
            #pragma unroll
            for (int nf = 0; nf < 4; nf++)
                acc[i][nf] = __builtin_amdgcn_mfma_f32_16x16x32_bf16(Af[i], Bf[nf], acc[i][nf], 0, 0, 0);
        __syncthreads();
    }

    const float inv3 = 1.0f / 3.0f;
    const float fnv = (float)nv;
    #pragma unroll
    for (int i = 0; i < 4; i++) {
        const int dout = mh * 128 + wm * 64 + i * 16 + l4 * 4;
        const float4 bb = *reinterpret_cast<const float4*>(b2 + dout);
        #pragma unroll
        for (int nf = 0; nf < 4; nf++) {
            const int c = col0 + wn * 64 + nf * 16 + l15;
            const size_t xoff = ((size_t)b * L_ + c) * D_ + dout;
            const float4 xr = *reinterpret_cast<const float4*>(x + xoff);
            float4 o;
            o.x = xr.x + (acc[i][nf][0] + fnv * bb.x) * inv3;
            o.y = xr.y + (acc[i][nf][1] + fnv * bb.y) * inv3;
            o.z = xr.z + (acc[i][nf][2] + fnv * bb.z) * inv3;
            o.w = xr.w + (acc[i][nf][3] + fnv * bb.w) * inv3;
            *reinterpret_cast<float4*>(yout + xoff) = o;
        }
    }
}

// ---- 8. LayerNorm in-place on d_out ----
__global__ void ln_kernel(float* __restrict__ y, const float* __restrict__ gamma,
                          const float* __restrict__ beta) {
    int row = blockIdx.x * 4 + (threadIdx.x >> 6);
    int lane = threadIdx.x & 63;
    size_t base = (size_t)row * D_ + lane * 4;
    float4 v = *reinterpret_cast<const float4*>(y + base);
    float s = v.x + v.y + v.z + v.w;
    float s2 = v.x * v.x + v.y * v.y + v.z * v.z + v.w * v.w;
    #pragma unroll
    for (int d = 32; d; d >>= 1) { s += __shfl_xor(s, d); s2 += __shfl_xor(s2, d); }
    float mu = s * (1.0f / D_);
    float var = s2 * (1.0f / D_) - mu * mu;
    float inv = 1.0f / sqrtf(var + 1e-5f);
    float4 g = *reinterpret_cast<const float4*>(gamma + lane * 4);
    float4 be = *reinterpret_cast<const float4*>(beta + lane * 4);
    float4 o;
    o.x = (v.x - mu) * inv * g.x + be.x;
    o.y = (v.y - mu) * inv * g.y + be.y;
    o.z = (v.z - mu) * inv * g.z + be.z;
    o.w = (v.w - mu) * inv * g.w + be.w;
    *reinterpret_cast<float4*>(y + base) = o;
}

extern "C" void kernel_launch(void* const* d_in, const int* in_sizes, int n_in,
                              void* d_out, int out_size, void* d_ws, size_t ws_size,
                              hipStream_t stream) {
    const float* x     = (const float*)d_in[0];
    const float* W1    = (const float*)d_in[1];
    const float* b1    = (const float*)d_in[2];
    const float* W2    = (const float*)d_in[3];
    const float* b2    = (const float*)d_in[4];
    const float* gamma = (const float*)d_in[5];
    const float* beta  = (const float*)d_in[6];
    float* out = (float*)d_out;

    char* ws = (char*)d_ws;
    size_t off = 0;
    auto walloc = [&](size_t bytes) -> void* {
        void* pp = ws + off;
        off += (bytes + 255) & ~(size_t)255;
        return pp;
    };
    unsigned short* xb      = (unsigned short*)walloc((size_t)B_ * L_ * D_ * 2);
    unsigned short* out1g   = (unsigned short*)walloc((size_t)B_ * 3 * LPMAX * C_ * 2);
    float* series           = (float*)walloc((size_t)B_ * L_ * 4);
    float* mag2             = (float*)walloc((size_t)B_ * 513 * 4);
    int* periods            = (int*)walloc((size_t)B_ * 3 * 4);
    double* tw              = (double*)walloc(1024 * 16);
    unsigned short* W1r     = (unsigned short*)walloc((size_t)C_ * K1 * 2);
    unsigned short* W2r     = (unsigned short*)walloc((size_t)D_ * K2 * 2);
    unsigned short* zeropad = (unsigned short*)walloc(1024);

    hipMemsetAsync(zeropad, 0, 1024, stream);
    prep_kernel<<<B_ * L_ / 4, 256, 0, stream>>>(x, xb, series);
    tw_kernel<<<4, 256, 0, stream>>>(tw);
    repack_kernel<<<(C_ * K1 + D_ * K2 + 255) / 256, 256, 0, stream>>>(W1, W2, W1r, W2r);
    dft_kernel<<<B_ * 513, 64, 0, stream>>>(series, tw, mag2);
    topk_kernel<<<B_, 64, 0, stream>>>(mag2, periods);
    conv1_kernel<<<B_ * 3 * 12, 256, 0, stream>>>(xb, W1r, b1, periods, out1g, zeropad);
    conv2_kernel<<<B_ * 16, 256, 0, stream>>>(out1g, W2r, b2, periods, x, out, zeropad);
    ln_kernel<<<B_ * L_ / 4, 256, 0, stream>>>(out, gamma, beta);
}

// Round 5
// 619.539 us; speedup vs baseline: 1.4022x; 1.0487x over previous
//
#include <hip/hip_runtime.h>
#include <hip/hip_bf16.h>
#include <math.h>

#define B_ 64
#define L_ 1024
#define D_ 256
#define C_ 128
#define LPMAX 1536
#define K1 2304   // 9 taps * 256
#define K2 1152   // 9 taps * 128

typedef __bf16 bf16x8 __attribute__((ext_vector_type(8)));
typedef float f32x4 __attribute__((ext_vector_type(4)));

__device__ __forceinline__ unsigned short f2bf(float f) {
    __hip_bfloat16 h = __float2bfloat16(f);
    return __builtin_bit_cast(unsigned short, h);
}

__device__ __forceinline__ float gelu_exact(float f) {
    return 0.5f * f * (1.0f + erff(f * 0.70710678118654752440f));
}

// async global->LDS: lds dest is wave-uniform base; HW adds lane*16
__device__ __forceinline__ void gl16(const unsigned short* g, unsigned short* l) {
    __builtin_amdgcn_global_load_lds(
        (const __attribute__((address_space(1))) unsigned int*)g,
        (__attribute__((address_space(3))) unsigned int*)l, 16, 0, 0);
}

// ---- 1. cast x to bf16 + channel-mean series ----
__global__ void prep_kernel(const float* __restrict__ x, unsigned short* __restrict__ xb,
                            float* __restrict__ series) {
    int row = blockIdx.x * 4 + (threadIdx.x >> 6);
    int lane = threadIdx.x & 63;
    size_t base = (size_t)row * D_ + lane * 4;
    float4 v = *reinterpret_cast<const float4*>(x + base);
    ushort4 o;
    o.x = f2bf(v.x); o.y = f2bf(v.y); o.z = f2bf(v.z); o.w = f2bf(v.w);
    *reinterpret_cast<ushort4*>(xb + base) = o;
    float s = v.x + v.y + v.z + v.w;
    #pragma unroll
    for (int d = 32; d; d >>= 1) s += __shfl_xor(s, d);
    if (lane == 0) series[row] = s * (1.0f / D_);
}

// ---- 2. twiddle table (double) ----
__global__ void tw_kernel(double* __restrict__ tw) {
    int j = blockIdx.x * 256 + threadIdx.x;
    if (j < 1024) {
        double a = -2.0 * 3.14159265358979323846 * (double)j / 1024.0;
        tw[2 * j] = cos(a);
        tw[2 * j + 1] = sin(a);
    }
}

// ---- 3. repack weights to bf16 GEMM layout ----
__global__ void repack_kernel(const float* __restrict__ W1, const float* __restrict__ W2,
                              unsigned short* __restrict__ W1r, unsigned short* __restrict__ W2r) {
    int i = blockIdx.x * 256 + threadIdx.x;
    if (i < C_ * K1) {
        int c = i / K1, k = i % K1;
        int tap = k >> 8, d = k & 255;
        int dt = tap / 3, dp = tap % 3;
        W1r[i] = f2bf(W1[((c * D_ + d) * 3 + dt) * 3 + dp]);
    } else {
        int i2 = i - C_ * K1;
        if (i2 < D_ * K2) {
            int dout = i2 / K2, k = i2 % K2;
            int tap = k >> 7, cc = k & 127;
            int dt = tap / 3, dp = tap % 3;
            W2r[i2] = f2bf(W2[((dout * C_ + cc) * 3 + dt) * 3 + dp]);
        }
    }
}

// ---- 4. DFT magnitude^2 (double accumulate) ----
__global__ void dft_kernel(const float* __restrict__ series, const double* __restrict__ tw,
                           float* __restrict__ mag2) {
    int bk = blockIdx.x;
    int k = bk % 513, b = bk / 513;
    int lane = threadIdx.x;
    const float* s = series + (size_t)b * L_;
    double re = 0.0, im = 0.0;
    #pragma unroll 4
    for (int i = 0; i < 16; i++) {
        int l = lane + 64 * i;
        int idx = (k * l) & 1023;
        double sv = (double)s[l];
        re += sv * tw[2 * idx];
        im += sv * tw[2 * idx + 1];
    }
    #pragma unroll
    for (int d = 32; d; d >>= 1) { re += __shfl_down(re, d); im += __shfl_down(im, d); }
    if (lane == 0) mag2[bk] = (k == 0) ? 0.0f : (float)(re * re + im * im);
}

// ---- 5. top-3, wave-parallel argmax (tie -> lowest index) ----
__global__ void topk_kernel(const float* __restrict__ mag2, int* __restrict__ periods) {
    int b = blockIdx.x;
    int lane = threadIdx.x;
    const float* m = mag2 + b * 513;
    float v[9]; int kid[9];
    #pragma unroll
    for (int r = 0; r < 9; r++) {
        int k = r * 64 + lane;
        kid[r] = k;
        v[r] = (k < 513) ? m[k] : -1.0f;
    }
    int s0 = -1, s1 = -1;
    for (int j = 0; j < 3; j++) {
        float best = -1.0f; int bi = 0x7fffffff;
        #pragma unroll
        for (int r = 0; r < 9; r++) {
            bool skip = (kid[r] == s0) || (kid[r] == s1) || (kid[r] >= 513);
            if (!skip && (v[r] > best || (v[r] == best && kid[r] < bi))) { best = v[r]; bi = kid[r]; }
        }
        #pragma unroll
        for (int d = 32; d; d >>= 1) {
            float ov = __shfl_xor(best, d);
            int oi = __shfl_xor(bi, d);
            if (ov > best || (ov == best && oi < bi)) { best = ov; bi = oi; }
        }
        if (lane == 0) periods[b * 3 + j] = bi + 1;
        if (j == 0) s0 = bi; else if (j == 1) s1 = bi;
    }
}

// ---- 6. conv1 (256->128) + bias + GELU, output col-major bf16 ----
// 128x128 tile, BK=32, counted-vmcnt double-buffer pipeline, XCD-grouped blocks
__global__ __launch_bounds__(256, 4)
void conv1_kernel(const unsigned short* __restrict__ xb,
                  const unsigned short* __restrict__ W1r,
                  const float* __restrict__ b1,
                  const int* __restrict__ periods,
                  unsigned short* __restrict__ out1g,
                  const unsigned short* __restrict__ zeropad) {
    __shared__ __align__(16) unsigned short lA[2][4096];
    __shared__ __align__(16) unsigned short lB[2][4096];

    // XCD-grouped decode: xcd = blk&7 handles b in [xcd*8, xcd*8+8)
    const int blk = blockIdx.x;
    const int xcd = blk & 7;
    const int li = blk >> 3;            // 0..287
    const int b = xcd * 8 + li / 36;
    const int rem = li % 36;
    const int j = rem / 12, tile = rem % 12;

    const int p = periods[b * 3 + j];
    if (p <= 1) return;
    const int T = (L_ + p - 1) / p;
    const int Lp = T * p;
    const int col0 = tile * 128;
    if (col0 >= Lp) return;

    const int tid = threadIdx.x;
    const int w = tid >> 6, lane = tid & 63;
    const int wm = w >> 1, wn = w & 1;
    const int l15 = lane & 15, l4 = lane >> 4;

    const unsigned short* xbb = xb + (size_t)b * L_ * D_;

    int cq0 = col0 + lane, cq1 = col0 + 64 + lane;
    int pp0 = cq0 % p, tt0 = cq0 / p;
    int pp1 = cq1 % p, tt1 = cq1 / p;

    int aoff[4], boff[4];
    #pragma unroll
    for (int i = 0; i < 4; i++) aoff[i] = l4 * 1024 + (wm * 64 + i * 16 + l15) * 8;
    #pragma unroll
    for (int nf = 0; nf < 4; nf++) boff[nf] = l4 * 1024 + (wn * 64 + nf * 16 + l15) * 8;

    f32x4 acc[4][4];
    #pragma unroll
    for (int i = 0; i < 4; i++)
        #pragma unroll
        for (int nf = 0; nf < 4; nf++)
            acc[i][nf] = f32x4{0.f, 0.f, 0.f, 0.f};

    const unsigned short* srcB0 = zeropad;
    const unsigned short* srcB1 = zeropad;
    int koffA = 0;

    auto settap = [&](int tap) {
        const int dt = tap / 3, dp = tap - 3 * dt;
        const int off = (dt - 1) * p + dp - 1;
        koffA = tap * 256;
        bool ok0 = (pp0 + dp >= 1) && (pp0 + dp <= p) && (tt0 + dt >= 1) && (tt0 + dt <= T) &&
                   (cq0 < Lp) && (cq0 + off < L_);
        bool ok1 = (pp1 + dp >= 1) && (pp1 + dp <= p) && (tt1 + dt >= 1) && (tt1 + dt <= T) &&
                   (cq1 < Lp) && (cq1 + off < L_);
        srcB0 = ok0 ? (xbb + (size_t)(cq0 + off) * D_) : zeropad;
        srcB1 = ok1 ? (xbb + (size_t)(cq1 + off) * D_) : zeropad;
    };

    auto stage = [&](int buf, int kk) {
        unsigned short* la = lA[buf];
        unsigned short* lb = lB[buf];
        const int kb = kk * 32 + w * 8;
        gl16(W1r + (size_t)lane * K1 + koffA + kb, la + w * 1024);
        gl16(W1r + (size_t)(64 + lane) * K1 + koffA + kb, la + w * 1024 + 512);
        gl16(srcB0 + kb, lb + w * 1024);
        gl16(srcB1 + kb, lb + w * 1024 + 512);
    };

    settap(0);
    stage(0, 0);

    int tap = 0;
    for (int s = 0; s < 72; s++) {
        const int cur = s & 1;
        const int sn = s + 1;
        if (sn < 72) {
            if ((sn & 7) == 0) settap(++tap);
            stage(cur ^ 1, sn & 7);
            asm volatile("s_waitcnt vmcnt(4)" ::: "memory");
        } else {
            asm volatile("s_waitcnt vmcnt(0)" ::: "memory");
        }
        __builtin_amdgcn_s_barrier();
        __builtin_amdgcn_sched_barrier(0);
        __builtin_amdgcn_s_setprio(1);
        {
            const unsigned short* la = lA[cur];
            const unsigned short* lb = lB[cur];
            bf16x8 Af[4], Bf[4];
            #pragma unroll
            for (int i = 0; i < 4; i++) Af[i] = *reinterpret_cast<const bf16x8*>(la + aoff[i]);
            #pragma unroll
            for (int nf = 0; nf < 4; nf++) Bf[nf] = *reinterpret_cast<const bf16x8*>(lb + boff[nf]);
            #pragma unroll
            for (int i = 0; i < 4; i++)
                #pragma unroll
                for (int nf = 0; nf < 4; nf++)
                    acc[i][nf] = __builtin_amdgcn_mfma_f32_16x16x32_bf16(Af[i], Bf[nf], acc[i][nf], 0, 0, 0);
        }
        __builtin_amdgcn_s_setprio(0);
        asm volatile("s_waitcnt lgkmcnt(0)" ::: "memory");
        __builtin_amdgcn_sched_barrier(0);
        __builtin_amdgcn_s_barrier();
    }

    const size_t ob = (size_t)(b * 3 + j) * LPMAX * C_;
    #pragma unroll
    for (int i = 0; i < 4; i++) {
        const int ch = wm * 64 + i * 16 + l4 * 4;
        const float4 bias = *reinterpret_cast<const float4*>(b1 + ch);
        #pragma unroll
        for (int nf = 0; nf < 4; nf++) {
            const int c = col0 + wn * 64 + nf * 16 + l15;
            if (c < Lp) {
                ushort4 o;
                o.x = f2bf(gelu_exact(acc[i][nf][0] + bias.x));
                o.y = f2bf(gelu_exact(acc[i][nf][1] + bias.y));
                o.z = f2bf(gelu_exact(acc[i][nf][2] + bias.z));
                o.w = f2bf(gelu_exact(acc[i][nf][3] + bias.w));
                *reinterpret_cast<ushort4*>(out1g + ob + (size_t)c * C_ + ch) = o;
            }
        }
    }
}

// ---- 7. conv2 (128->256) summed over 3 periods + residual; writes y to d_out ----
__global__ __launch_bounds__(256, 4)
void conv2_kernel(const unsigned short* __restrict__ out1g,
                  const unsigned short* __restrict__ W2r,
                  const float* __restrict__ b2,
                  const int* __restrict__ periods,
                  const float* __restrict__ x,
                  float* __restrict__ yout,
                  const unsigned short* __restrict__ zeropad) {
    __shared__ __align__(16) unsigned short lA[2][4096];
    __shared__ __align__(16) unsigned short lB[2][4096];

    // XCD-grouped decode: xcd = blk&7 handles b in [xcd*8, xcd*8+8)
    const int blk = blockIdx.x;
    const int xcd = blk & 7;
    const int li = blk >> 3;            // 0..127
    const int b = xcd * 8 + (li >> 4);
    const int rem = li & 15;
    const int mh = rem & 1;
    const int tile = rem >> 1;
    const int col0 = tile * 128;

    const int tid = threadIdx.x;
    const int w = tid >> 6, lane = tid & 63;
    const int wm = w >> 1, wn = w & 1;
    const int l15 = lane & 15, l4 = lane >> 4;

    int cq0 = col0 + lane, cq1 = col0 + 64 + lane;

    int aoff[4], boff[4];
    #pragma unroll
    for (int i = 0; i < 4; i++) aoff[i] = l4 * 1024 + (wm * 64 + i * 16 + l15) * 8;
    #pragma unroll
    for (int nf = 0; nf < 4; nf++) boff[nf] = l4 * 1024 + (wn * 64 + nf * 16 + l15) * 8;

    f32x4 acc[4][4];
    #pragma unroll
    for (int i = 0; i < 4; i++)
        #pragma unroll
        for (int nf = 0; nf < 4; nf++)
            acc[i][nf] = f32x4{0.f, 0.f, 0.f, 0.f};

    int jn = 0, tap9 = 0;
    int pj = periods[b * 3];
    int Tj = (L_ + pj - 1) / pj;
    const unsigned short* bbj = out1g + (size_t)(b * 3) * LPMAX * C_;
    int pp0 = cq0 % pj, tt0 = cq0 / pj;
    int pp1 = cq1 % pj, tt1 = cq1 / pj;
    int nv = 0;
    #pragma unroll
    for (int jj = 0; jj < 3; jj++) nv += (periods[b * 3 + jj] > 1) ? 1 : 0;

    const unsigned short* srcB0 = zeropad;
    const unsigned short* srcB1 = zeropad;
    int koffA = 0;

    auto settap = [&](int tap) {
        const int dt = tap / 3, dp = tap - 3 * dt;
        const int off = (dt - 1) * pj + dp - 1;
        koffA = tap * 128;
        bool okj = pj > 1;
        bool ok0 = okj && (pp0 + dp >= 1) && (pp0 + dp <= pj) && (tt0 + dt >= 1) && (tt0 + dt <= Tj);
        bool ok1 = okj && (pp1 + dp >= 1) && (pp1 + dp <= pj) && (tt1 + dt >= 1) && (tt1 + dt <= Tj);
        srcB0 = ok0 ? (bbj + (size_t)(cq0 + off) * C_) : zeropad;
        srcB1 = ok1 ? (bbj + (size_t)(cq1 + off) * C_) : zeropad;
    };

    auto stage = [&](int buf, int kk) {
        unsigned short* la = lA[buf];
        unsigned short* lb = lB[buf];
        const int kb = kk * 32 + w * 8;
        gl16(W2r + (size_t)(mh * 128 + lane) * K2 + koffA + kb, la + w * 1024);
        gl16(W2r + (size_t)(mh * 128 + 64 + lane) * K2 + koffA + kb, la + w * 1024 + 512);
        gl16(srcB0 + kb, lb + w * 1024);
        gl16(srcB1 + kb, lb + w * 1024 + 512);
    };

    settap(0);
    stage(0, 0);

    for (int s = 0; s < 108; s++) {
        const int cur = s & 1;
        const int sn = s + 1;
        if (sn < 108) {
            if ((sn & 3) == 0) {
                if (++tap9 == 9) {
                    tap9 = 0;
                    jn++;
                    pj = periods[b * 3 + jn];
                    Tj = (L_ + pj - 1) / pj;
                    bbj = out1g + (size_t)(b * 3 + jn) * LPMAX * C_;
                    pp0 = cq0 % pj; tt0 = cq0 / pj;
                    pp1 = cq1 % pj; tt1 = cq1 / pj;
                }
                settap(tap9);
            }
            stage(cur ^ 1, sn & 3);
            asm volatile("s_waitcnt vmcnt(4)" ::: "memory");
        } else {
            asm volatile("s_waitcnt vmcnt(0)" ::: "memory");
        }
        __builtin_amdgcn_s_barrier();
        __builtin_amdgcn_sched_barrier(0);
        __builtin_amdgcn_s_setprio(1);
        {
            const unsigned short* la = lA[cur];
            const unsigned short* lb = lB[cur];
            bf16x8 Af[4], Bf[4];
            #pragma unroll
            for (int i = 0; i < 4; i++) Af[i] = *reinterpret_cast<const bf16x8*>(la + aoff[i]);
            #pragma unroll
            for (int nf = 0; nf < 4; nf++) Bf[nf] = *reinterpret_cast<const bf16x8*>(lb + boff[nf]);
            #pragma unroll
            for (int i = 0; i < 4; i++)
                #pragma unroll
                for (int nf = 0; nf < 4; nf++)
                    acc[i][nf] = __builtin_amdgcn_mfma_f32_16x16x32_bf16(Af[i], Bf[nf], acc[i][nf], 0, 0, 0);
        }
        __builtin_amdgcn_s_setprio(0);
        asm volatile("s_waitcnt lgkmcnt(0)" ::: "memory");
        __builtin_amdgcn_sched_barrier(0);
        __builtin_amdgcn_s_barrier();
    }

    const float inv3 = 1.0f / 3.0f;
    const float fnv = (float)nv;
    #pragma unroll
    for (int i = 0; i < 4; i++) {
        const int dout = mh * 128 + wm * 64 + i * 16 + l4 * 4;
        const float4 bb = *reinterpret_cast<const float4*>(b2 + dout);
        #pragma unroll
        for (int nf = 0; nf < 4; nf++) {
            const int c = col0 + wn * 64 + nf * 16 + l15;
            const size_t xoff = ((size_t)b * L_ + c) * D_ + dout;
            const float4 xr = *reinterpret_cast<const float4*>(x + xoff);
            float4 o;
            o.x = xr.x + (acc[i][nf][0] + fnv * bb.x) * inv3;
            o.y = xr.y + (acc[i][nf][1] + fnv * bb.y) * inv3;
            o.z = xr.z + (acc[i][nf][2] + fnv * bb.z) * inv3;
            o.w = xr.w + (acc[i][nf][3] + fnv * bb.w) * inv3;
            *reinterpret_cast<float4*>(yout + xoff) = o;
        }
    }
}

// ---- 8. LayerNorm in-place on d_out ----
__global__ void ln_kernel(float* __restrict__ y, const float* __restrict__ gamma,
                          const float* __restrict__ beta) {
    int row = blockIdx.x * 4 + (threadIdx.x >> 6);
    int lane = threadIdx.x & 63;
    size_t base = (size_t)row * D_ + lane * 4;
    float4 v = *reinterpret_cast<const float4*>(y + base);
    float s = v.x + v.y + v.z + v.w;
    float s2 = v.x * v.x + v.y * v.y + v.z * v.z + v.w * v.w;
    #pragma unroll
    for (int d = 32; d; d >>= 1) { s += __shfl_xor(s, d); s2 += __shfl_xor(s2, d); }
    float mu = s * (1.0f / D_);
    float var = s2 * (1.0f / D_) - mu * mu;
    float inv = 1.0f / sqrtf(var + 1e-5f);
    float4 g = *reinterpret_cast<const float4*>(gamma + lane * 4);
    float4 be = *reinterpret_cast<const float4*>(beta + lane * 4);
    float4 o;
    o.x = (v.x - mu) * inv * g.x + be.x;
    o.y = (v.y - mu) * inv * g.y + be.y;
    o.z = (v.z - mu) * inv * g.z + be.z;
    o.w = (v.w - mu) * inv * g.w + be.w;
    *reinterpret_cast<float4*>(y + base) = o;
}

extern "C" void kernel_launch(void* const* d_in, const int* in_sizes, int n_in,
                              void* d_out, int out_size, void* d_ws, size_t ws_size,
                              hipStream_t stream) {
    const float* x     = (const float*)d_in[0];
    const float* W1    = (const float*)d_in[1];
    const float* b1    = (const float*)d_in[2];
    const float* W2    = (const float*)d_in[3];
    const float* b2    = (const float*)d_in[4];
    const float* gamma = (const float*)d_in[5];
    const float* beta  = (const float*)d_in[6];
    float* out = (float*)d_out;

    char* ws = (char*)d_ws;
    size_t off = 0;
    auto walloc = [&](size_t bytes) -> void* {
        void* pp = ws + off;
        off += (bytes + 255) & ~(size_t)255;
        return pp;
    };
    unsigned short* xb      = (unsigned short*)walloc((size_t)B_ * L_ * D_ * 2);
    unsigned short* out1g   = (unsigned short*)walloc((size_t)B_ * 3 * LPMAX * C_ * 2);
    float* series           = (float*)walloc((size_t)B_ * L_ * 4);
    float* mag2             = (float*)walloc((size_t)B_ * 513 * 4);
    int* periods            = (int*)walloc((size_t)B_ * 3 * 4);
    double* tw              = (double*)walloc(1024 * 16);
    unsigned short* W1r     = (unsigned short*)walloc((size_t)C_ * K1 * 2);
    unsigned short* W2r     = (unsigned short*)walloc((size_t)D_ * K2 * 2);
    unsigned short* zeropad = (unsigned short*)walloc(1024);

    hipMemsetAsync(zeropad, 0, 1024, stream);
    prep_kernel<<<B_ * L_ / 4, 256, 0, stream>>>(x, xb, series);
    tw_kernel<<<4, 256, 0, stream>>>(tw);
    repack_kernel<<<(C_ * K1 + D_ * K2 + 255) / 256, 256, 0, stream>>>(W1, W2, W1r, W2r);
    dft_kernel<<<B_ * 513, 64, 0, stream>>>(series, tw, mag2);
    topk_kernel<<<B_, 64, 0, stream>>>(mag2, periods);
    conv1_kernel<<<B_ * 3 * 12, 256, 0, stream>>>(xb, W1r, b1, periods, out1g, zeropad);
    conv2_kernel<<<B_ * 16, 256, 0, stream>>>(out1g, W2r, b2, periods, x, out, zeropad);
    ln_kernel<<<B_ * L_ / 4, 256, 0, stream>>>(out, gamma, beta);
}

// Round 7
// 575.222 us; speedup vs baseline: 1.5103x; 1.0770x over previous
//
#include <hip/hip_runtime.h>
#include <hip/hip_bf16.h>
#include <math.h>

#define B_ 64
#define L_ 1024
#define D_ 256
#define C_ 128
#define LPMAX 1536
#define K1 2304   // 9 taps * 256
#define K2 1152   // 9 taps * 128

typedef __bf16 bf16x8 __attribute__((ext_vector_type(8)));
typedef float f32x4 __attribute__((ext_vector_type(4)));

__device__ __forceinline__ unsigned short f2bf(float f) {
    __hip_bfloat16 h = __float2bfloat16(f);
    return __builtin_bit_cast(unsigned short, h);
}

__device__ __forceinline__ float gelu_exact(float f) {
    return 0.5f * f * (1.0f + erff(f * 0.70710678118654752440f));
}

// async global->LDS: global src is per-lane, LDS dest = wave-uniform base + lane*16
__device__ __forceinline__ void gl16(const unsigned short* g, unsigned short* l) {
    __builtin_amdgcn_global_load_lds(
        (const __attribute__((address_space(1))) unsigned int*)g,
        (__attribute__((address_space(3))) unsigned int*)l, 16, 0, 0);
}

// ---- 1. cast x to bf16 + channel-mean series ----
__global__ void prep_kernel(const float* __restrict__ x, unsigned short* __restrict__ xb,
                            float* __restrict__ series) {
    int row = blockIdx.x * 4 + (threadIdx.x >> 6);
    int lane = threadIdx.x & 63;
    size_t base = (size_t)row * D_ + lane * 4;
    float4 v = *reinterpret_cast<const float4*>(x + base);
    ushort4 o;
    o.x = f2bf(v.x); o.y = f2bf(v.y); o.z = f2bf(v.z); o.w = f2bf(v.w);
    *reinterpret_cast<ushort4*>(xb + base) = o;
    float s = v.x + v.y + v.z + v.w;
    #pragma unroll
    for (int d = 32; d; d >>= 1) s += __shfl_xor(s, d);
    if (lane == 0) series[row] = s * (1.0f / D_);
}

// ---- 2. twiddle table (double) ----
__global__ void tw_kernel(double* __restrict__ tw) {
    int j = blockIdx.x * 256 + threadIdx.x;
    if (j < 1024) {
        double a = -2.0 * 3.14159265358979323846 * (double)j / 1024.0;
        tw[2 * j] = cos(a);
        tw[2 * j + 1] = sin(a);
    }
}

// ---- 3. repack weights to bf16 GEMM layout ----
__global__ void repack_kernel(const float* __restrict__ W1, const float* __restrict__ W2,
                              unsigned short* __restrict__ W1r, unsigned short* __restrict__ W2r) {
    int i = blockIdx.x * 256 + threadIdx.x;
    if (i < C_ * K1) {
        int c = i / K1, k = i % K1;
        int tap = k >> 8, d = k & 255;
        int dt = tap / 3, dp = tap % 3;
        W1r[i] = f2bf(W1[((c * D_ + d) * 3 + dt) * 3 + dp]);
    } else {
        int i2 = i - C_ * K1;
        if (i2 < D_ * K2) {
            int dout = i2 / K2, k = i2 % K2;
            int tap = k >> 7, cc = k & 127;
            int dt = tap / 3, dp = tap % 3;
            W2r[i2] = f2bf(W2[((dout * C_ + cc) * 3 + dt) * 3 + dp]);
        }
    }
}

// ---- 4. DFT magnitude^2 (double accumulate) ----
__global__ void dft_kernel(const float* __restrict__ series, const double* __restrict__ tw,
                           float* __restrict__ mag2) {
    int bk = blockIdx.x;
    int k = bk % 513, b = bk / 513;
    int lane = threadIdx.x;
    const float* s = series + (size_t)b * L_;
    double re = 0.0, im = 0.0;
    #pragma unroll 4
    for (int i = 0; i < 16; i++) {
        int l = lane + 64 * i;
        int idx = (k * l) & 1023;
        double sv = (double)s[l];
        re += sv * tw[2 * idx];
        im += sv * tw[2 * idx + 1];
    }
    #pragma unroll
    for (int d = 32; d; d >>= 1) { re += __shfl_down(re, d); im += __shfl_down(im, d); }
    if (lane == 0) mag2[bk] = (k == 0) ? 0.0f : (float)(re * re + im * im);
}

// ---- 5. top-3, wave-parallel argmax (tie -> lowest index) ----
__global__ void topk_kernel(const float* __restrict__ mag2, int* __restrict__ periods) {
    int b = blockIdx.x;
    int lane = threadIdx.x;
    const float* m = mag2 + b * 513;
    float v[9]; int kid[9];
    #pragma unroll
    for (int r = 0; r < 9; r++) {
        int k = r * 64 + lane;
        kid[r] = k;
        v[r] = (k < 513) ? m[k] : -1.0f;
    }
    int s0 = -1, s1 = -1;
    for (int j = 0; j < 3; j++) {
        float best = -1.0f; int bi = 0x7fffffff;
        #pragma unroll
        for (int r = 0; r < 9; r++) {
            bool skip = (kid[r] == s0) || (kid[r] == s1) || (kid[r] >= 513);
            if (!skip && (v[r] > best || (v[r] == best && kid[r] < bi))) { best = v[r]; bi = kid[r]; }
        }
        #pragma unroll
        for (int d = 32; d; d >>= 1) {
            float ov = __shfl_xor(best, d);
            int oi = __shfl_xor(bi, d);
            if (ov > best || (ov == best && oi < bi)) { best = ov; bi = oi; }
        }
        if (lane == 0) periods[b * 3 + j] = bi + 1;
        if (j == 0) s0 = bi; else if (j == 1) s1 = bi;
    }
}

// ---- 6. conv1 (256->128) + bias + GELU, output col-major bf16 ----
// 128x128 tile; per phase: (dt,kk32) unit = 192-col B window + 3 dp-taps of A,
// 48 MFMA/wave between barriers, counted vmcnt(9), masks via LDS zero-col redirect.
__global__ __launch_bounds__(256, 2)
void conv1_kernel(const unsigned short* __restrict__ xb,
                  const unsigned short* __restrict__ W1r,
                  const float* __restrict__ b1,
                  const int* __restrict__ periods,
                  unsigned short* __restrict__ out1g) {
    __shared__ __align__(16) unsigned short sA[2][12288];  // [3 dp][4 koct][128 rows][8]
    __shared__ __align__(16) unsigned short sB[2][6656];   // [4 koct][208 cols][8]

    const int blk = blockIdx.x;
    const int xcd = blk & 7;
    const int li = blk >> 3;            // 0..287
    const int b = xcd * 8 + li / 36;
    const int rem = li % 36;
    const int j = rem / 12, tile = rem % 12;

    const int p = periods[b * 3 + j];
    if (p <= 1) return;
    const int T = (L_ + p - 1) / p;
    const int Lp = T * p;
    const int col0 = tile * 128;
    if (col0 >= Lp) return;

    const int tid = threadIdx.x;
    const int w = tid >> 6, lane = tid & 63;
    const int wm = w >> 1, wn = w & 1;
    const int l15 = lane & 15, l4 = lane >> 4;

    const unsigned short* xbb = xb + (size_t)b * L_ * D_;

    int cols[4], ppv[4], ttv[4];
    #pragma unroll
    for (int nf = 0; nf < 4; nf++) {
        cols[nf] = col0 + wn * 64 + nf * 16 + l15;
        ppv[nf] = cols[nf] % p;
        ttv[nf] = cols[nf] / p;
    }

    int arow[4];
    #pragma unroll
    for (int i = 0; i < 4; i++) arow[i] = l4 * 1024 + (wm * 64 + i * 16 + l15) * 8;
    const int zoff = l4 * 1664 + (192 + l15) * 8;
    int bbase[4];
    #pragma unroll
    for (int nf = 0; nf < 4; nf++) bbase[nf] = l4 * 1664 + (wn * 64 + nf * 16 + l15 + 31) * 8;

    f32x4 acc[4][4];
    #pragma unroll
    for (int i = 0; i < 4; i++)
        #pragma unroll
        for (int nf = 0; nf < 4; nf++)
            acc[i][nf] = f32x4{0.f, 0.f, 0.f, 0.f};

    // zero the redirect columns (cols 192..207 of each k-octet plane, both buffers)
    {
        int bf = tid >> 7, r = tid & 127;
        int oct = r >> 5, q = r & 31;
        ushort4 z = {0, 0, 0, 0};
        *reinterpret_cast<ushort4*>(&sB[bf][oct * 1664 + 1536 + q * 4]) = z;
    }

    int locv[3][4];
    auto setdt = [&](int dt) {
        #pragma unroll
        for (int dp = 0; dp < 3; dp++)
            #pragma unroll
            for (int nf = 0; nf < 4; nf++) {
                int pd = ppv[nf] + dp, td = ttv[nf] + dt;
                int t = cols[nf] + (dt - 1) * p + dp - 1;
                bool ok = (pd >= 1) && (pd <= p) && (td >= 1) && (td <= T) &&
                          (cols[nf] < Lp) && (t < L_);
                locv[dp][nf] = ok ? (bbase[nf] + dp * 8) : zoff;
            }
    };

    auto stage = [&](int buf, int dt, int kk) {
        const int win0 = col0 + (dt - 1) * p - 32;
        const int kb = kk * 32 + w * 8;
        unsigned short* la = sA[buf];
        unsigned short* lb = sB[buf];
        #pragma unroll
        for (int q = 0; q < 6; q++) {
            const int dp = q >> 1, half = q & 1;
            const int row = half * 64 + lane;
            gl16(W1r + (size_t)row * K1 + (dt * 3 + dp) * 256 + kb,
                 la + dp * 4096 + w * 1024 + half * 512);
        }
        #pragma unroll
        for (int s = 0; s < 3; s++) {
            int c = win0 + s * 64 + lane;
            c = c < 0 ? 0 : (c > L_ - 1 ? L_ - 1 : c);
            gl16(xbb + (size_t)c * D_ + kb, lb + w * 1664 + s * 512);
        }
    };

    setdt(0);
    stage(0, 0, 0);
    __syncthreads();

    for (int ph = 0; ph < 24; ph++) {
        const int cur = ph & 1;
        const int pn = ph + 1;
        if (pn < 24) {
            stage(cur ^ 1, pn >> 3, pn & 7);
            asm volatile("s_waitcnt vmcnt(9)" ::: "memory");
        } else {
            asm volatile("s_waitcnt vmcnt(0)" ::: "memory");
        }
        __builtin_amdgcn_s_barrier();
        __builtin_amdgcn_sched_barrier(0);
        __builtin_amdgcn_s_setprio(1);
        {
            const unsigned short* la = sA[cur];
            const unsigned short* lb = sB[cur];
            #pragma unroll
            for (int dp = 0; dp < 3; dp++) {
                bf16x8 Af[4], Bf[4];
                #pragma unroll
                for (int i = 0; i < 4; i++)
                    Af[i] = *reinterpret_cast<const bf16x8*>(la + dp * 4096 + arow[i]);
                #pragma unroll
                for (int nf = 0; nf < 4; nf++)
                    Bf[nf] = *reinterpret_cast<const bf16x8*>(lb + locv[dp][nf]);
                #pragma unroll
                for (int i = 0; i < 4; i++)
                    #pragma unroll
                    for (int nf = 0; nf < 4; nf++)
                        acc[i][nf] = __builtin_amdgcn_mfma_f32_16x16x32_bf16(Af[i], Bf[nf], acc[i][nf], 0, 0, 0);
            }
        }
        __builtin_amdgcn_s_setprio(0);
        asm volatile("s_waitcnt lgkmcnt(0)" ::: "memory");
        __builtin_amdgcn_sched_barrier(0);
        __builtin_amdgcn_s_barrier();
        // masks for the NEXT phase's dt-group: update when pn starts a new group of 8
        if (pn < 24 && (pn & 7) == 0) setdt(pn >> 3);
    }

    const size_t ob = (size_t)(b * 3 + j) * LPMAX * C_;
    #pragma unroll
    for (int i = 0; i < 4; i++) {
        const int ch = wm * 64 + i * 16 + l4 * 4;
        const float4 bias = *reinterpret_cast<const float4*>(b1 + ch);
        #pragma unroll
        for (int nf = 0; nf < 4; nf++) {
            const int c = cols[nf];
            if (c < Lp) {
                ushort4 o;
                o.x = f2bf(gelu_exact(acc[i][nf][0] + bias.x));
                o.y = f2bf(gelu_exact(acc[i][nf][1] + bias.y));
                o.z = f2bf(gelu_exact(acc[i][nf][2] + bias.z));
                o.w = f2bf(gelu_exact(acc[i][nf][3] + bias.w));
                *reinterpret_cast<ushort4*>(out1g + ob + (size_t)c * C_ + ch) = o;
            }
        }
    }
}

// ---- 7. conv2 (128->256) summed over 3 periods + residual; writes y to d_out ----
// Same phase structure: (j,dt,kk32) unit, 48 MFMA/wave per barrier-pair.
__global__ __launch_bounds__(256, 2)
void conv2_kernel(const unsigned short* __restrict__ out1g,
                  const unsigned short* __restrict__ W2r,
                  const float* __restrict__ b2,
                  const int* __restrict__ periods,
                  const float* __restrict__ x,
                  float* __restrict__ yout) {
    __shared__ __align__(16) unsigned short sA[2][12288];
    __shared__ __align__(16) unsigned short sB[2][6656];

    const int blk = blockIdx.x;
    const int xcd = blk & 7;
    const int li = blk >> 3;            // 0..127
    const int b = xcd * 8 + (li >> 4);
    const int rem = li & 15;
    const int mh = rem & 1;
    const int tile = rem >> 1;
    const int col0 = tile * 128;

    const int tid = threadIdx.x;
    const int w = tid >> 6, lane = tid & 63;
    const int wm = w >> 1, wn = w & 1;
    const int l15 = lane & 15, l4 = lane >> 4;

    int p_all[3];
    #pragma unroll
    for (int jj = 0; jj < 3; jj++) p_all[jj] = periods[b * 3 + jj];
    const int nv = (p_all[0] > 1) + (p_all[1] > 1) + (p_all[2] > 1);

    int cols[4];
    #pragma unroll
    for (int nf = 0; nf < 4; nf++) cols[nf] = col0 + wn * 64 + nf * 16 + l15;

    int arow[4];
    #pragma unroll
    for (int i = 0; i < 4; i++) arow[i] = l4 * 1024 + (wm * 64 + i * 16 + l15) * 8;
    const int zoff = l4 * 1664 + (192 + l15) * 8;
    int bbase[4];
    #pragma unroll
    for (int nf = 0; nf < 4; nf++) bbase[nf] = l4 * 1664 + (wn * 64 + nf * 16 + l15 + 31) * 8;

    f32x4 acc[4][4];
    #pragma unroll
    for (int i = 0; i < 4; i++)
        #pragma unroll
        for (int nf = 0; nf < 4; nf++)
            acc[i][nf] = f32x4{0.f, 0.f, 0.f, 0.f};

    {
        int bf = tid >> 7, r = tid & 127;
        int oct = r >> 5, q = r & 31;
        ushort4 z = {0, 0, 0, 0};
        *reinterpret_cast<ushort4*>(&sB[bf][oct * 1664 + 1536 + q * 4]) = z;
    }

    int locv[3][4];
    auto setjdt = [&](int jn, int dt) {
        const int pj = p_all[jn];
        const int Tj = (L_ + pj - 1) / pj;
        const bool okj = pj > 1;
        #pragma unroll
        for (int dp = 0; dp < 3; dp++)
            #pragma unroll
            for (int nf = 0; nf < 4; nf++) {
                int pv = cols[nf] % pj, tv = cols[nf] / pj;
                int pd = pv + dp, td = tv + dt;
                bool ok = okj && (pd >= 1) && (pd <= pj) && (td >= 1) && (td <= Tj);
                locv[dp][nf] = ok ? (bbase[nf] + dp * 8) : zoff;
            }
    };

    auto stage = [&](int buf, int jn, int dt, int kk) {
        const int pj = p_all[jn];
        const unsigned short* bbj = out1g + (size_t)(b * 3 + jn) * LPMAX * C_;
        const int win0 = col0 + (dt - 1) * pj - 32;
        const int kb = kk * 32 + w * 8;
        unsigned short* la = sA[buf];
        unsigned short* lb = sB[buf];
        #pragma unroll
        for (int q = 0; q < 6; q++) {
            const int dp = q >> 1, half = q & 1;
            const int row = mh * 128 + half * 64 + lane;
            gl16(W2r + (size_t)row * K2 + (dt * 3 + dp) * 128 + kb,
                 la + dp * 4096 + w * 1024 + half * 512);
        }
        #pragma unroll
        for (int s = 0; s < 3; s++) {
            int c = win0 + s * 64 + lane;
            c = c < 0 ? 0 : (c > LPMAX - 1 ? LPMAX - 1 : c);
            gl16(bbj + (size_t)c * C_ + kb, lb + w * 1664 + s * 512);
        }
    };

    setjdt(0, 0);
    stage(0, 0, 0, 0);
    __syncthreads();

    for (int ph = 0; ph < 36; ph++) {
        const int cur = ph & 1;
        const int pn = ph + 1;
        if (pn < 36) {
            stage(cur ^ 1, pn / 12, (pn / 4) % 3, pn & 3);
            asm volatile("s_waitcnt vmcnt(9)" ::: "memory");
        } else {
            asm volatile("s_waitcnt vmcnt(0)" ::: "memory");
        }
        __builtin_amdgcn_s_barrier();
        __builtin_amdgcn_sched_barrier(0);
        __builtin_amdgcn_s_setprio(1);
        {
            const unsigned short* la = sA[cur];
            const unsigned short* lb = sB[cur];
            #pragma unroll
            for (int dp = 0; dp < 3; dp++) {
                bf16x8 Af[4], Bf[4];
                #pragma unroll
                for (int i = 0; i < 4; i++)
                    Af[i] = *reinterpret_cast<const bf16x8*>(la + dp * 4096 + arow[i]);
                #pragma unroll
                for (int nf = 0; nf < 4; nf++)
                    Bf[nf] = *reinterpret_cast<const bf16x8*>(lb + locv[dp][nf]);
                #pragma unroll
                for (int i = 0; i < 4; i++)
                    #pragma unroll
                    for (int nf = 0; nf < 4; nf++)
                        acc[i][nf] = __builtin_amdgcn_mfma_f32_16x16x32_bf16(Af[i], Bf[nf], acc[i][nf], 0, 0, 0);
            }
        }
        __builtin_amdgcn_s_setprio(0);
        asm volatile("s_waitcnt lgkmcnt(0)" ::: "memory");
        __builtin_amdgcn_sched_barrier(0);
        __builtin_amdgcn_s_barrier();
        // masks for the NEXT phase's (jn,dt)-group: update when pn starts a new group of 4
        if (pn < 36 && (pn & 3) == 0) setjdt(pn / 12, (pn / 4) % 3);
    }

    const float inv3 = 1.0f / 3.0f;
    const float fnv = (float)nv;
    #pragma unroll
    for (int i = 0; i < 4; i++) {
        const int dout = mh * 128 + wm * 64 + i * 16 + l4 * 4;
        const float4 bb = *reinterpret_cast<const float4*>(b2 + dout);
        #pragma unroll
        for (int nf = 0; nf < 4; nf++) {
            const size_t xoff = ((size_t)b * L_ + cols[nf]) * D_ + dout;
            const float4 xr = *reinterpret_cast<const float4*>(x + xoff);
            float4 o;
            o.x = xr.x + (acc[i][nf][0] + fnv * bb.x) * inv3;
            o.y = xr.y + (acc[i][nf][1] + fnv * bb.y) * inv3;
            o.z = xr.z + (acc[i][nf][2] + fnv * bb.z) * inv3;
            o.w = xr.w + (acc[i][nf][3] + fnv * bb.w) * inv3;
            *reinterpret_cast<float4*>(yout + xoff) = o;
        }
    }
}

// ---- 8. LayerNorm in-place on d_out ----
__global__ void ln_kernel(float* __restrict__ y, const float* __restrict__ gamma,
                          const float* __restrict__ beta) {
    int row = blockIdx.x * 4 + (threadIdx.x >> 6);
    int lane = threadIdx.x & 63;
    size_t base = (size_t)row * D_ + lane * 4;
    float4 v = *reinterpret_cast<const float4*>(y + base);
    float s = v.x + v.y + v.z + v.w;
    float s2 = v.x * v.x + v.y * v.y + v.z * v.z + v.w * v.w;
    #pragma unroll
    for (int d = 32; d; d >>= 1) { s += __shfl_xor(s, d); s2 += __shfl_xor(s2, d); }
    float mu = s * (1.0f / D_);
    float var = s2 * (1.0f / D_) - mu * mu;
    float inv = 1.0f / sqrtf(var + 1e-5f);
    float4 g = *reinterpret_cast<const float4*>(gamma + lane * 4);
    float4 be = *reinterpret_cast<const float4*>(beta + lane * 4);
    float4 o;
    o.x = (v.x - mu) * inv * g.x + be.x;
    o.y = (v.y - mu) * inv * g.y + be.y;
    o.z = (v.z - mu) * inv * g.z + be.z;
    o.w = (v.w - mu) * inv * g.w + be.w;
    *reinterpret_cast<float4*>(y + base) = o;
}

extern "C" void kernel_launch(void* const* d_in, const int* in_sizes, int n_in,
                              void* d_out, int out_size, void* d_ws, size_t ws_size,
                              hipStream_t stream) {
    const float* x     = (const float*)d_in[0];
    const float* W1    = (const float*)d_in[1];
    const float* b1    = (const float*)d_in[2];
    const float* W2    = (const float*)d_in[3];
    const float* b2    = (const float*)d_in[4];
    const float* gamma = (const float*)d_in[5];
    const float* beta  = (const float*)d_in[6];
    float* out = (float*)d_out;

    char* ws = (char*)d_ws;
    size_t off = 0;
    auto walloc = [&](size_t bytes) -> void* {
        void* pp = ws + off;
        off += (bytes + 255) & ~(size_t)255;
        return pp;
    };
    unsigned short* xb    = (unsigned short*)walloc((size_t)B_ * L_ * D_ * 2);
    unsigned short* out1g = (unsigned short*)walloc((size_t)B_ * 3 * LPMAX * C_ * 2);
    float* series         = (float*)walloc((size_t)B_ * L_ * 4);
    float* mag2           = (float*)walloc((size_t)B_ * 513 * 4);
    int* periods          = (int*)walloc((size_t)B_ * 3 * 4);
    double* tw            = (double*)walloc(1024 * 16);
    unsigned short* W1r   = (unsigned short*)walloc((size_t)C_ * K1 * 2);
    unsigned short* W2r   = (unsigned short*)walloc((size_t)D_ * K2 * 2);

    prep_kernel<<<B_ * L_ / 4, 256, 0, stream>>>(x, xb, series);
    tw_kernel<<<4, 256, 0, stream>>>(tw);
    repack_kernel<<<(C_ * K1 + D_ * K2 + 255) / 256, 256, 0, stream>>>(W1, W2, W1r, W2r);
    dft_kernel<<<B_ * 513, 64, 0, stream>>>(series, tw, mag2);
    topk_kernel<<<B_, 64, 0, stream>>>(mag2, periods);
    conv1_kernel<<<B_ * 3 * 12, 256, 0, stream>>>(xb, W1r, b1, periods, out1g);
    conv2_kernel<<<B_ * 16, 256, 0, stream>>>(out1g, W2r, b2, periods, x, out);
    ln_kernel<<<B_ * L_ / 4, 256, 0, stream>>>(out, gamma, beta);
}

// Round 8
// 439.462 us; speedup vs baseline: 1.9768x; 1.3089x over previous
//
#include <hip/hip_runtime.h>
#include <hip/hip_bf16.h>
#include <math.h>

#define B_ 64
#define L_ 1024
#define D_ 256
#define C_ 128
#define LPMAX 1536

typedef __bf16 bf16x8 __attribute__((ext_vector_type(8)));
typedef float f32x4 __attribute__((ext_vector_type(4)));

__device__ __forceinline__ unsigned short f2bf(float f) {
    __hip_bfloat16 h = __float2bfloat16(f);
    return __builtin_bit_cast(unsigned short, h);
}

__device__ __forceinline__ float gelu_exact(float f) {
    return 0.5f * f * (1.0f + erff(f * 0.70710678118654752440f));
}

// async global->LDS: global src is per-lane, LDS dest = wave-uniform base + lane*16
__device__ __forceinline__ void gl16(const unsigned short* g, unsigned short* l) {
    __builtin_amdgcn_global_load_lds(
        (const __attribute__((address_space(1))) unsigned int*)g,
        (__attribute__((address_space(3))) unsigned int*)l, 16, 0, 0);
}

// ---- 1. cast x to bf16 + channel-mean series ----
__global__ void prep_kernel(const float* __restrict__ x, unsigned short* __restrict__ xb,
                            float* __restrict__ series) {
    int row = blockIdx.x * 4 + (threadIdx.x >> 6);
    int lane = threadIdx.x & 63;
    size_t base = (size_t)row * D_ + lane * 4;
    float4 v = *reinterpret_cast<const float4*>(x + base);
    ushort4 o;
    o.x = f2bf(v.x); o.y = f2bf(v.y); o.z = f2bf(v.z); o.w = f2bf(v.w);
    *reinterpret_cast<ushort4*>(xb + base) = o;
    float s = v.x + v.y + v.z + v.w;
    #pragma unroll
    for (int d = 32; d; d >>= 1) s += __shfl_xor(s, d);
    if (lane == 0) series[row] = s * (1.0f / D_);
}

// ---- 2. twiddle table (double) ----
__global__ void tw_kernel(double* __restrict__ tw) {
    int j = blockIdx.x * 256 + threadIdx.x;
    if (j < 1024) {
        double a = -2.0 * 3.14159265358979323846 * (double)j / 1024.0;
        tw[2 * j] = cos(a);
        tw[2 * j + 1] = sin(a);
    }
}

// ---- 3. repack weights into per-phase LDS images ----
// W1s: [tap(9)][kk(8)][rb(8)][q(4)][rr(16)][8]  (row=rb*16+rr in 0..127, d=kk*32+q*8+e)
// W2s: [tap(9)][kk(4)][rb(16)][q(4)][rr(16)][8] (row=rb*16+rr in 0..255, c=kk*32+q*8+e)
__global__ void repack_kernel(const float* __restrict__ W1, const float* __restrict__ W2,
                              unsigned short* __restrict__ W1s, unsigned short* __restrict__ W2s) {
    int i = blockIdx.x * 256 + threadIdx.x;
    if (i < 294912) {
        int img = i >> 12;               // tap*8 + kk
        int tap = img >> 3, kk = img & 7;
        int within = i & 4095;
        int rb = within >> 9, q = (within >> 7) & 3, rr = (within >> 3) & 15, e = i & 7;
        int c = rb * 16 + rr, d = kk * 32 + q * 8 + e;
        int dt = tap / 3, dp = tap % 3;
        W1s[i] = f2bf(W1[((c * D_ + d) * 3 + dt) * 3 + dp]);
    } else {
        int i2 = i - 294912;
        if (i2 < 294912) {
            int img = i2 >> 13;          // tap*4 + kk
            int tap = img >> 2, kk = img & 3;
            int within = i2 & 8191;
            int rb = within >> 9, q = (within >> 7) & 3, rr = (within >> 3) & 15, e = i2 & 7;
            int dout = rb * 16 + rr, cin = kk * 32 + q * 8 + e;
            int dt = tap / 3, dp = tap % 3;
            W2s[i2] = f2bf(W2[((dout * C_ + cin) * 3 + dt) * 3 + dp]);
        }
    }
}

// ---- 4. DFT magnitude^2 (double accumulate) ----
__global__ void dft_kernel(const float* __restrict__ series, const double* __restrict__ tw,
                           float* __restrict__ mag2) {
    int bk = blockIdx.x;
    int k = bk % 513, b = bk / 513;
    int lane = threadIdx.x;
    const float* s = series + (size_t)b * L_;
    double re = 0.0, im = 0.0;
    #pragma unroll 4
    for (int i = 0; i < 16; i++) {
        int l = lane + 64 * i;
        int idx = (k * l) & 1023;
        double sv = (double)s[l];
        re += sv * tw[2 * idx];
        im += sv * tw[2 * idx + 1];
    }
    #pragma unroll
    for (int d = 32; d; d >>= 1) { re += __shfl_down(re, d); im += __shfl_down(im, d); }
    if (lane == 0) mag2[bk] = (k == 0) ? 0.0f : (float)(re * re + im * im);
}

// ---- 5. top-3, wave-parallel argmax (tie -> lowest index) ----
__global__ void topk_kernel(const float* __restrict__ mag2, int* __restrict__ periods) {
    int b = blockIdx.x;
    int lane = threadIdx.x;
    const float* m = mag2 + b * 513;
    float v[9]; int kid[9];
    #pragma unroll
    for (int r = 0; r < 9; r++) {
        int k = r * 64 + lane;
        kid[r] = k;
        v[r] = (k < 513) ? m[k] : -1.0f;
    }
    int s0 = -1, s1 = -1;
    for (int j = 0; j < 3; j++) {
        float best = -1.0f; int bi = 0x7fffffff;
        #pragma unroll
        for (int r = 0; r < 9; r++) {
            bool skip = (kid[r] == s0) || (kid[r] == s1) || (kid[r] >= 513);
            if (!skip && (v[r] > best || (v[r] == best && kid[r] < bi))) { best = v[r]; bi = kid[r]; }
        }
        #pragma unroll
        for (int d = 32; d; d >>= 1) {
            float ov = __shfl_xor(best, d);
            int oi = __shfl_xor(bi, d);
            if (ov > best || (ov == best && oi < bi)) { best = ov; bi = oi; }
        }
        if (lane == 0) periods[b * 3 + j] = bi + 1;
        if (j == 0) s0 = bi; else if (j == 1) s1 = bi;
    }
}

// ---- 6. conv1 (256->128) + bias + GELU, output col-major bf16 ----
// 128x128 tile; phase (dt,kk32): A = 3dp-tap phase-image (linear gl16),
// B = 192-col window, 4 lanes/column coalesced. 48 MFMA/wave/phase, vmcnt(9).
__global__ __launch_bounds__(256, 2)
void conv1_kernel(const unsigned short* __restrict__ xb,
                  const unsigned short* __restrict__ W1s,
                  const float* __restrict__ b1,
                  const int* __restrict__ periods,
                  unsigned short* __restrict__ out1g) {
    __shared__ __align__(16) unsigned short sA[2][12288];  // [dp(3)][sub(8)][512]
    __shared__ __align__(16) unsigned short sB[2][6656];   // [chunk(13)][q(4)][cc(16)][8]; chunk12=zeros

    const int blk = blockIdx.x;
    const int xcd = blk & 7;
    const int li = blk >> 3;            // 0..287
    const int b = xcd * 8 + li / 36;
    const int rem = li % 36;
    const int j = rem / 12, tile = rem % 12;

    const int p = periods[b * 3 + j];
    if (p <= 1) return;
    const int T = (L_ + p - 1) / p;
    const int Lp = T * p;
    const int col0 = tile * 128;
    if (col0 >= Lp) return;

    const int tid = threadIdx.x;
    const int w = tid >> 6, lane = tid & 63;
    const int wm = w >> 1, wn = w & 1;
    const int l15 = lane & 15, l4 = lane >> 4;

    const unsigned short* xbb = xb + (size_t)b * L_ * D_;

    int cols[4], ppv[4], ttv[4];
    #pragma unroll
    for (int nf = 0; nf < 4; nf++) {
        cols[nf] = col0 + wn * 64 + nf * 16 + l15;
        ppv[nf] = cols[nf] % p;
        ttv[nf] = cols[nf] / p;
    }

    // fragment offsets (ushort units)
    int arow4[4];
    #pragma unroll
    for (int i = 0; i < 4; i++) arow4[i] = (wm * 4 + i) * 512 + l4 * 128 + l15 * 8;
    const int zoff = 12 * 512 + l4 * 128 + l15 * 8;
    int bok[3][4];
    #pragma unroll
    for (int dp = 0; dp < 3; dp++)
        #pragma unroll
        for (int nf = 0; nf < 4; nf++) {
            int rc = wn * 64 + nf * 16 + 31 + dp + l15;
            bok[dp][nf] = (rc >> 4) * 512 + l4 * 128 + (rc & 15) * 8;
        }

    f32x4 acc[4][4];
    #pragma unroll
    for (int i = 0; i < 4; i++)
        #pragma unroll
        for (int nf = 0; nf < 4; nf++)
            acc[i][nf] = f32x4{0.f, 0.f, 0.f, 0.f};

    // zero the redirect chunk (chunk 12, both buffers)
    {
        int bf = tid >> 7, r = tid & 127;
        ushort4 z = {0, 0, 0, 0};
        *reinterpret_cast<ushort4*>(&sB[bf][12 * 512 + r * 4]) = z;
    }

    int locv[3][4];
    auto setdt = [&](int dt) {
        #pragma unroll
        for (int dp = 0; dp < 3; dp++)
            #pragma unroll
            for (int nf = 0; nf < 4; nf++) {
                int pd = ppv[nf] + dp, td = ttv[nf] + dt;
                int t = cols[nf] + (dt - 1) * p + dp - 1;
                bool ok = (pd >= 1) && (pd <= p) && (td >= 1) && (td <= T) &&
                          (cols[nf] < Lp) && (t < L_);
                locv[dp][nf] = ok ? bok[dp][nf] : zoff;
            }
    };

    auto stage = [&](int buf, int dt, int kk) {
        unsigned short* la = sA[buf];
        unsigned short* lb = sB[buf];
        // A: 6 linear gl16 per wave (piece pi = w*6+s6: dp=pi>>3, sub=pi&7)
        #pragma unroll
        for (int s6 = 0; s6 < 6; s6++) {
            int pi = w * 6 + s6;
            int dp = pi >> 3, sub = pi & 7;
            gl16(W1s + (size_t)((dt * 3 + dp) * 8 + kk) * 4096 + sub * 512 + lane * 8,
                 la + pi * 512);
        }
        // B: 3 gl16 per wave, 4 lanes per column (chunk ci = w*3+s3)
        const int win0 = col0 + (dt - 1) * p - 32;
        #pragma unroll
        for (int s3 = 0; s3 < 3; s3++) {
            int ci = w * 3 + s3;
            int c = win0 + ci * 16 + l15;
            c = c < 0 ? 0 : (c > L_ - 1 ? L_ - 1 : c);
            gl16(xbb + (size_t)c * D_ + kk * 32 + l4 * 8, lb + ci * 512);
        }
    };

    setdt(0);
    stage(0, 0, 0);
    __syncthreads();

    for (int ph = 0; ph < 24; ph++) {
        const int cur = ph & 1;
        const int pn = ph + 1;
        if (pn < 24) {
            stage(cur ^ 1, pn >> 3, pn & 7);
            asm volatile("s_waitcnt vmcnt(9)" ::: "memory");
        } else {
            asm volatile("s_waitcnt vmcnt(0)" ::: "memory");
        }
        __builtin_amdgcn_s_barrier();
        __builtin_amdgcn_sched_barrier(0);
        __builtin_amdgcn_s_setprio(1);
        {
            const unsigned short* la = sA[cur];
            const unsigned short* lb = sB[cur];
            #pragma unroll
            for (int dp = 0; dp < 3; dp++) {
                bf16x8 Af[4], Bf[4];
                #pragma unroll
                for (int i = 0; i < 4; i++)
                    Af[i] = *reinterpret_cast<const bf16x8*>(la + dp * 4096 + arow4[i]);
                #pragma unroll
                for (int nf = 0; nf < 4; nf++)
                    Bf[nf] = *reinterpret_cast<const bf16x8*>(lb + locv[dp][nf]);
                #pragma unroll
                for (int i = 0; i < 4; i++)
                    #pragma unroll
                    for (int nf = 0; nf < 4; nf++)
                        acc[i][nf] = __builtin_amdgcn_mfma_f32_16x16x32_bf16(Af[i], Bf[nf], acc[i][nf], 0, 0, 0);
            }
        }
        __builtin_amdgcn_s_setprio(0);
        asm volatile("s_waitcnt lgkmcnt(0)" ::: "memory");
        __builtin_amdgcn_sched_barrier(0);
        __builtin_amdgcn_s_barrier();
        if (pn < 24 && (pn & 7) == 0) setdt(pn >> 3);
    }

    const size_t ob = (size_t)(b * 3 + j) * LPMAX * C_;
    #pragma unroll
    for (int i = 0; i < 4; i++) {
        const int ch = wm * 64 + i * 16 + l4 * 4;
        const float4 bias = *reinterpret_cast<const float4*>(b1 + ch);
        #pragma unroll
        for (int nf = 0; nf < 4; nf++) {
            const int c = cols[nf];
            if (c < Lp) {
                ushort4 o;
                o.x = f2bf(gelu_exact(acc[i][nf][0] + bias.x));
                o.y = f2bf(gelu_exact(acc[i][nf][1] + bias.y));
                o.z = f2bf(gelu_exact(acc[i][nf][2] + bias.z));
                o.w = f2bf(gelu_exact(acc[i][nf][3] + bias.w));
                *reinterpret_cast<ushort4*>(out1g + ob + (size_t)c * C_ + ch) = o;
            }
        }
    }
}

// ---- 7. conv2 (128->256) summed over 3 periods + residual; writes y to d_out ----
__global__ __launch_bounds__(256, 2)
void conv2_kernel(const unsigned short* __restrict__ out1g,
                  const unsigned short* __restrict__ W2s,
                  const float* __restrict__ b2,
                  const int* __restrict__ periods,
                  const float* __restrict__ x,
                  float* __restrict__ yout) {
    __shared__ __align__(16) unsigned short sA[2][12288];
    __shared__ __align__(16) unsigned short sB[2][6656];

    const int blk = blockIdx.x;
    const int xcd = blk & 7;
    const int li = blk >> 3;            // 0..127
    const int b = xcd * 8 + (li >> 4);
    const int rem = li & 15;
    const int mh = rem & 1;
    const int tile = rem >> 1;
    const int col0 = tile * 128;

    const int tid = threadIdx.x;
    const int w = tid >> 6, lane = tid & 63;
    const int wm = w >> 1, wn = w & 1;
    const int l15 = lane & 15, l4 = lane >> 4;

    int p_all[3];
    #pragma unroll
    for (int jj = 0; jj < 3; jj++) p_all[jj] = periods[b * 3 + jj];
    const int nv = (p_all[0] > 1) + (p_all[1] > 1) + (p_all[2] > 1);

    int cols[4];
    #pragma unroll
    for (int nf = 0; nf < 4; nf++) cols[nf] = col0 + wn * 64 + nf * 16 + l15;

    int arow4[4];
    #pragma unroll
    for (int i = 0; i < 4; i++) arow4[i] = (wm * 4 + i) * 512 + l4 * 128 + l15 * 8;
    const int zoff = 12 * 512 + l4 * 128 + l15 * 8;
    int bok[3][4];
    #pragma unroll
    for (int dp = 0; dp < 3; dp++)
        #pragma unroll
        for (int nf = 0; nf < 4; nf++) {
            int rc = wn * 64 + nf * 16 + 31 + dp + l15;
            bok[dp][nf] = (rc >> 4) * 512 + l4 * 128 + (rc & 15) * 8;
        }

    f32x4 acc[4][4];
    #pragma unroll
    for (int i = 0; i < 4; i++)
        #pragma unroll
        for (int nf = 0; nf < 4; nf++)
            acc[i][nf] = f32x4{0.f, 0.f, 0.f, 0.f};

    {
        int bf = tid >> 7, r = tid & 127;
        ushort4 z = {0, 0, 0, 0};
        *reinterpret_cast<ushort4*>(&sB[bf][12 * 512 + r * 4]) = z;
    }

    int locv[3][4];
    auto setjdt = [&](int jn, int dt) {
        const int pj = p_all[jn];
        const int Tj = (L_ + pj - 1) / pj;
        const bool okj = pj > 1;
        #pragma unroll
        for (int dp = 0; dp < 3; dp++)
            #pragma unroll
            for (int nf = 0; nf < 4; nf++) {
                int pv = cols[nf] % pj, tv = cols[nf] / pj;
                int pd = pv + dp, td = tv + dt;
                bool ok = okj && (pd >= 1) && (pd <= pj) && (td >= 1) && (td <= Tj);
                locv[dp][nf] = ok ? bok[dp][nf] : zoff;
            }
    };

    auto stage = [&](int buf, int jn, int dt, int kk) {
        const int pj = p_all[jn];
        const unsigned short* bbj = out1g + (size_t)(b * 3 + jn) * LPMAX * C_;
        unsigned short* la = sA[buf];
        unsigned short* lb = sB[buf];
        #pragma unroll
        for (int s6 = 0; s6 < 6; s6++) {
            int pi = w * 6 + s6;
            int dp = pi >> 3, sub = pi & 7;
            gl16(W2s + (size_t)((dt * 3 + dp) * 4 + kk) * 8192 + mh * 4096 + sub * 512 + lane * 8,
                 la + pi * 512);
        }
        const int win0 = col0 + (dt - 1) * pj - 32;
        #pragma unroll
        for (int s3 = 0; s3 < 3; s3++) {
            int ci = w * 3 + s3;
            int c = win0 + ci * 16 + l15;
            c = c < 0 ? 0 : (c > LPMAX - 1 ? LPMAX - 1 : c);
            gl16(bbj + (size_t)c * C_ + kk * 32 + l4 * 8, lb + ci * 512);
        }
    };

    setjdt(0, 0);
    stage(0, 0, 0, 0);
    __syncthreads();

    for (int ph = 0; ph < 36; ph++) {
        const int cur = ph & 1;
        const int pn = ph + 1;
        if (pn < 36) {
            stage(cur ^ 1, pn / 12, (pn / 4) % 3, pn & 3);
            asm volatile("s_waitcnt vmcnt(9)" ::: "memory");
        } else {
            asm volatile("s_waitcnt vmcnt(0)" ::: "memory");
        }
        __builtin_amdgcn_s_barrier();
        __builtin_amdgcn_sched_barrier(0);
        __builtin_amdgcn_s_setprio(1);
        {
            const unsigned short* la = sA[cur];
            const unsigned short* lb = sB[cur];
            #pragma unroll
            for (int dp = 0; dp < 3; dp++) {
                bf16x8 Af[4], Bf[4];
                #pragma unroll
                for (int i = 0; i < 4; i++)
                    Af[i] = *reinterpret_cast<const bf16x8*>(la + dp * 4096 + arow4[i]);
                #pragma unroll
                for (int nf = 0; nf < 4; nf++)
                    Bf[nf] = *reinterpret_cast<const bf16x8*>(lb + locv[dp][nf]);
                #pragma unroll
                for (int i = 0; i < 4; i++)
                    #pragma unroll
                    for (int nf = 0; nf < 4; nf++)
                        acc[i][nf] = __builtin_amdgcn_mfma_f32_16x16x32_bf16(Af[i], Bf[nf], acc[i][nf], 0, 0, 0);
            }
        }
        __builtin_amdgcn_s_setprio(0);
        asm volatile("s_waitcnt lgkmcnt(0)" ::: "memory");
        __builtin_amdgcn_sched_barrier(0);
        __builtin_amdgcn_s_barrier();
        if (pn < 36 && (pn & 3) == 0) setjdt(pn / 12, (pn / 4) % 3);
    }

    const float inv3 = 1.0f / 3.0f;
    const float fnv = (float)nv;
    #pragma unroll
    for (int i = 0; i < 4; i++) {
        const int dout = mh * 128 + wm * 64 + i * 16 + l4 * 4;
        const float4 bb = *reinterpret_cast<const float4*>(b2 + dout);
        #pragma unroll
        for (int nf = 0; nf < 4; nf++) {
            const size_t xoff = ((size_t)b * L_ + cols[nf]) * D_ + dout;
            const float4 xr = *reinterpret_cast<const float4*>(x + xoff);
            float4 o;
            o.x = xr.x + (acc[i][nf][0] + fnv * bb.x) * inv3;
            o.y = xr.y + (acc[i][nf][1] + fnv * bb.y) * inv3;
            o.z = xr.z + (acc[i][nf][2] + fnv * bb.z) * inv3;
            o.w = xr.w + (acc[i][nf][3] + fnv * bb.w) * inv3;
            *reinterpret_cast<float4*>(yout + xoff) = o;
        }
    }
}

// ---- 8. LayerNorm in-place on d_out ----
__global__ void ln_kernel(float* __restrict__ y, const float* __restrict__ gamma,
                          const float* __restrict__ beta) {
    int row = blockIdx.x * 4 + (threadIdx.x >> 6);
    int lane = threadIdx.x & 63;
    size_t base = (size_t)row * D_ + lane * 4;
    float4 v = *reinterpret_cast<const float4*>(y + base);
    float s = v.x + v.y + v.z + v.w;
    float s2 = v.x * v.x + v.y * v.y + v.z * v.z + v.w * v.w;
    #pragma unroll
    for (int d = 32; d; d >>= 1) { s += __shfl_xor(s, d); s2 += __shfl_xor(s2, d); }
    float mu = s * (1.0f / D_);
    float var = s2 * (1.0f / D_) - mu * mu;
    float inv = 1.0f / sqrtf(var + 1e-5f);
    float4 g = *reinterpret_cast<const float4*>(gamma + lane * 4);
    float4 be = *reinterpret_cast<const float4*>(beta + lane * 4);
    float4 o;
    o.x = (v.x - mu) * inv * g.x + be.x;
    o.y = (v.y - mu) * inv * g.y + be.y;
    o.z = (v.z - mu) * inv * g.z + be.z;
    o.w = (v.w - mu) * inv * g.w + be.w;
    *reinterpret_cast<float4*>(y + base) = o;
}

extern "C" void kernel_launch(void* const* d_in, const int* in_sizes, int n_in,
                              void* d_out, int out_size, void* d_ws, size_t ws_size,
                              hipStream_t stream) {
    const float* x     = (const float*)d_in[0];
    const float* W1    = (const float*)d_in[1];
    const float* b1    = (const float*)d_in[2];
    const float* W2    = (const float*)d_in[3];
    const float* b2    = (const float*)d_in[4];
    const float* gamma = (const float*)d_in[5];
    const float* beta  = (const float*)d_in[6];
    float* out = (float*)d_out;

    char* ws = (char*)d_ws;
    size_t off = 0;
    auto walloc = [&](size_t bytes) -> void* {
        void* pp = ws + off;
        off += (bytes + 255) & ~(size_t)255;
        return pp;
    };
    unsigned short* xb    = (unsigned short*)walloc((size_t)B_ * L_ * D_ * 2);
    unsigned short* out1g = (unsigned short*)walloc((size_t)B_ * 3 * LPMAX * C_ * 2);
    float* series         = (float*)walloc((size_t)B_ * L_ * 4);
    float* mag2           = (float*)walloc((size_t)B_ * 513 * 4);
    int* periods          = (int*)walloc((size_t)B_ * 3 * 4);
    double* tw            = (double*)walloc(1024 * 16);
    unsigned short* W1s   = (unsigned short*)walloc((size_t)294912 * 2);
    unsigned short* W2s   = (unsigned short*)walloc((size_t)294912 * 2);

    prep_kernel<<<B_ * L_ / 4, 256, 0, stream>>>(x, xb, series);
    tw_kernel<<<4, 256, 0, stream>>>(tw);
    repack_kernel<<<2304, 256, 0, stream>>>(W1, W2, W1s, W2s);
    dft_kernel<<<B_ * 513, 64, 0, stream>>>(series, tw, mag2);
    topk_kernel<<<B_, 64, 0, stream>>>(mag2, periods);
    conv1_kernel<<<B_ * 3 * 12, 256, 0, stream>>>(xb, W1s, b1, periods, out1g);
    conv2_kernel<<<B_ * 16, 256, 0, stream>>>(out1g, W2s, b2, periods, x, out);
    ln_kernel<<<B_ * L_ / 4, 256, 0, stream>>>(out, gamma, beta);
}